// Round 14
// baseline (1439.431 us; speedup 1.0000x reference)
//
#include <hip/hip_runtime.h>
#include <cstdint>
#include <cstddef>

#define B 128
#define T 64
#define IDIM 128
#define E 256
#define H 512
#define NT 1024

#define AT_STRIDE 34
#define AT_CH (128 * AT_STRIDE)   // 4352 floats per 128-k chunk

// LDS pool offsets (floats)
#define OFF_W   0                       // Wlds[640][32] = 20480
#define OFF_A   20480                   // At4[4][AT_CH] = 17408
#define OFF_HC  (OFF_A + 4 * AT_CH)     // hc[1024]
#define OFF_Z1  (OFF_HC + 1024)        // z1s[64]
#define OFF_RED (OFF_Z1 + 64)          // red[128]
#define OFF_BI  (OFF_RED + 128)        // bias[32]
#define POOL_F  (OFF_BI + 32)          // 39136 floats = 156544 B (<160K)

__device__ __forceinline__ float waveReduceSum(float v) {
    for (int off = 32; off > 0; off >>= 1) v += __shfl_xor(v, off, 64);
    return v;
}

__device__ __forceinline__ float fast_tanh(float v) {
    float a = fabsf(v);
    float e = __expf(-2.f * a);
    float r = (1.f - e) * __builtin_amdgcn_rcpf(1.f + e);
    return copysignf(r, v);
}

__device__ __forceinline__ float sigmoidf_(float x) {
    return 1.0f / (1.0f + __expf(-x));
}

// Coherent scalar accessors (bypass stale L1/L2; served at coherence point).
__device__ __forceinline__ float aload(const float* p) {
    return __hip_atomic_load(p, __ATOMIC_RELAXED, __HIP_MEMORY_SCOPE_AGENT);
}
__device__ __forceinline__ void astore(float* p, float v) {
    __hip_atomic_store(p, v, __ATOMIC_RELAXED, __HIP_MEMORY_SCOPE_AGENT);
}

// Coherent 16B load (async — must waitvm0() before using the result).
__device__ __forceinline__ float4 cload4(const float* p) {
    float4 v;
    asm volatile("global_load_dwordx4 %0, %1, off sc0 sc1" : "=v"(v) : "v"(p));
    return v;
}
__device__ __forceinline__ void waitvm0() {
    asm volatile("s_waitcnt vmcnt(0)" ::: "memory");
}

// ---------------------------------------------------------------------------
__global__ __launch_bounds__(256) void news_kernel(
    const float* __restrict__ in, const float* __restrict__ nW,
    const float* __restrict__ nb, float* __restrict__ x)
{
    int out_idx = blockIdx.x * 4 + (threadIdx.x >> 6);
    int lane = threadIdx.x & 63;
    const float4* src = (const float4*)(in + (size_t)out_idx * E);
    float4 a = src[lane];
    float4 wv = ((const float4*)nW)[lane];
    float s = a.x * wv.x + a.y * wv.y + a.z * wv.z + a.w * wv.w;
    s = waveReduceSum(s);
    if (lane == 0) x[out_idx] = s + nb[0];
}

// ---------------------------------------------------------------------------
__global__ __launch_bounds__(64) void z2_kernel(
    const float* __restrict__ x, const float* __restrict__ A2,
    const float* __restrict__ b2, float* __restrict__ z2)
{
    int b = blockIdx.x >> 7;
    int i = blockIdx.x & 127;
    int s = threadIdx.x;
    __shared__ float xs[T];
    xs[s] = x[((size_t)b * T + s) * IDIM + i];
    __syncthreads();
    float acc = b2[s];
    const float* arow = A2 + s * T;
#pragma unroll 8
    for (int tt = 0; tt < T; ++tt) acc += xs[tt] * arow[tt];
    z2[((size_t)b * IDIM + i) * T + s] = acc;
}

// ---------------------------------------------------------------------------
// Split per-quarter two-level barrier: 64 blocks = 8 groups x 8.
// Barrier duty on tid NT-1 (wave 15) — wave 0 is the softmax straggler.
__device__ __forceinline__ void qarrive(int* cnt, int q, int ns, int ph) {
    __syncthreads();                     // all waves drain vmem before arrive
    if (threadIdx.x == NT - 1) {
        asm volatile("s_waitcnt vmcnt(0) lgkmcnt(0)" ::: "memory");
        int* subp  = cnt + (q * 8 + (ns >> 3)) * 32;
        int* rootp = cnt + 1024 + q * 32;
        int old = __hip_atomic_fetch_add(subp, 1, __ATOMIC_RELAXED,
                                         __HIP_MEMORY_SCOPE_AGENT);
        if (old == ph * 8 - 1)
            __hip_atomic_fetch_add(rootp, 1, __ATOMIC_RELAXED,
                                   __HIP_MEMORY_SCOPE_AGENT);
    }
}
__device__ __forceinline__ void qwait(int* cnt, int q, int ph) {
    if (threadIdx.x == NT - 1) {
        int* rootp = cnt + 1024 + q * 32;
        int spins = 0;
        while (__hip_atomic_load(rootp, __ATOMIC_RELAXED,
                                 __HIP_MEMORY_SCOPE_AGENT) < ph * 8) {
            if (++spins > (1 << 16)) break;  // fail visibly, never hang
        }
    }
    __syncthreads();
}

// ---------------------------------------------------------------------------
// Persistent scan — R13 structure re-tiled to 1024 threads (16 waves/CU,
// ~48% occupancy vs 24%). Same 256 blocks, same split barriers, same LDS
// layout and numerics. VGPR-cliff rule holds: no live ranges extended
// across phases (hv shrinks 32->16 regs). k-reduce is two-stage (16->8->1).
__global__ __launch_bounds__(NT, 1) void scan_kernel(
    const float* __restrict__ x, const float* __restrict__ z2,
    const float* __restrict__ A1, const float* __restrict__ b1,
    const float* __restrict__ a3w,
    const float* __restrict__ Wih, const float* __restrict__ Whh,
    const float* __restrict__ bih, const float* __restrict__ bhh,
    float* __restrict__ wbuf, float* __restrict__ hbuf, float* __restrict__ cbuf,
    int* __restrict__ cnt, float* __restrict__ out)
{
    __shared__ float pool[POOL_F];
    float* Wlds = pool + OFF_W;
    float* At4  = pool + OFF_A;
    float* hcs  = pool + OFF_HC;
    float* z1s  = pool + OFF_Z1;
    float* redl = pool + OFF_RED;
    float* blds = pool + OFF_BI;

    const int tid  = threadIdx.x;
    const int bid  = blockIdx.x;
    const int lane = tid & 63, wave = tid >> 6;  // wave 0..15
    const int q = bid >> 6, ns = bid & 63;
    const int b0 = q * 32, n0 = ns * 8;
    const int ab = b0 + (ns >> 1);             // attn batch (pair-shared)
    const int par = ns & 1;                    // which wbuf half to write
    const int jg = lane & 7, bg = lane >> 3;   // compute tile coords
    const int half = tid >> 8;                 // h-staging: chunk 0..3
    const int sbh = (tid >> 3) & 31;           // batch row 0..31
    const int st8 = tid & 7;

    // one-time: weight slice (cols j = g*512 + n0 + nn; 4 gates x 8 n)
    for (int idx = tid; idx < 640 * 32; idx += NT) {
        int jj = idx / 640, k = idx - jj * 640;
        int j = (jj >> 3) * 512 + n0 + (jj & 7);
        Wlds[k * 32 + jj] = (k < 128) ? Wih[(size_t)j * 128 + k]
                                      : Whh[(size_t)j * 512 + (k - 128)];
    }
    if (tid < 32) {
        int j = (tid >> 3) * 512 + n0 + (tid & 7);
        blds[tid] = bih[j] + bhh[j];
    }

    // block-local cell state: thread tid<256 owns c[b0 + (tid>>3)][n0 + (tid&7)]
    float cown = 0.f;

    int ph = 0;
    for (int t = 0; t < T; ++t) {
        // -------- issue coherent h-tile prefetch (latency hides under attn)
        float4 hv[4];
        {
            const float* hrow = hbuf + (size_t)(b0 + sbh) * H + half * 128;
#pragma unroll
            for (int qq = 0; qq < 4; ++qq)
                hv[qq] = cload4(hrow + (st8 + 8 * qq) * 4);
        }

        // -------- phase A: attention (ALL blocks; pair-duplicated) ----------
        {
            hcs[tid] = (tid < H) ? aload(hbuf + (size_t)ab * H + tid)
                                 : aload(cbuf + (size_t)ab * H + (tid - H));
            __syncthreads();
            // z1: 4 rows per wave, scalar stride-64 LDS reads (2-way, free)
            for (int r = 0; r < 4; ++r) {
                int tt = r * 16 + wave;
                const float* row = A1 + (size_t)tt * (2 * H);
                float p = 0.f;
#pragma unroll
                for (int qq = 0; qq < 16; ++qq)
                    p += row[lane + qq * 64] * hcs[lane + qq * 64];
                p = waveReduceSum(p);
                if (lane == 0) z1s[tt] = p + b1[tt];
            }
            __syncthreads();
            // z3: 8 threads per driver row, 8 t each
            int i = tid >> 3, qt = tid & 7;
            const float* z2r = z2 + ((size_t)ab * IDIM + i) * T + qt * 8;
            const float* z1p = z1s + qt * 8;
            const float* a3p = a3w + qt * 8;
            float accz = 0.f;
#pragma unroll
            for (int qq = 0; qq < 2; ++qq) {
                float4 zv  = *(const float4*)(z2r + qq * 4);
                float4 z1v = *(const float4*)(z1p + qq * 4);
                float4 a3v = *(const float4*)(a3p + qq * 4);
                accz += fast_tanh(z1v.x + zv.x) * a3v.x
                      + fast_tanh(z1v.y + zv.y) * a3v.y
                      + fast_tanh(z1v.z + zv.z) * a3v.z
                      + fast_tanh(z1v.w + zv.w) * a3v.w;
            }
            accz += __shfl_xor(accz, 1, 64);
            accz += __shfl_xor(accz, 2, 64);
            accz += __shfl_xor(accz, 4, 64);
            if (qt == 0) redl[i] = accz;
            __syncthreads();
            if (wave == 0) {
                float v0 = redl[lane], v1 = redl[lane + 64];
                float m = fmaxf(v0, v1);
                for (int off = 32; off > 0; off >>= 1)
                    m = fmaxf(m, __shfl_xor(m, off, 64));
                float e0 = __expf(v0 - m), e1 = __expf(v1 - m);
                float inv = 1.0f / waveReduceSum(e0 + e1);
                const float* xt = x + ((size_t)ab * T + t) * IDIM;
                if (par == 0)
                    astore(wbuf + ab * IDIM + lane,      e0 * inv * xt[lane]);
                else
                    astore(wbuf + ab * IDIM + lane + 64, e1 * inv * xt[lane + 64]);
            }
        }

        // -------- ARRIVE #1 (wbuf published); tree propagates under B1 ------
        ++ph;
        qarrive(cnt, q, ns, ph);

        // -------- stage h-tile into LDS (transposed, stride-34) -------------
        waitvm0();
        {
#pragma unroll
            for (int qq = 0; qq < 4; ++qq) {
                float4 v = hv[qq];
                float* d = At4 + half * AT_CH
                         + ((st8 + 8 * qq) * 4) * AT_STRIDE + sbh;
                d[0] = v.x; d[AT_STRIDE] = v.y;
                d[2 * AT_STRIDE] = v.z; d[3 * AT_STRIDE] = v.w;
            }
        }
        __syncthreads();

        // -------- B1: h-part GEMM, wave k-split (32 kk each of 512) ---------
        float acc[4][4];   // [ji (j within group)][eb (b within group)]
#pragma unroll
        for (int a_ = 0; a_ < 4; ++a_)
#pragma unroll
            for (int b_ = 0; b_ < 4; ++b_) acc[a_][b_] = 0.f;
        {
            const float* Ab = At4 + (wave >> 2) * AT_CH
                            + ((wave & 3) * 32) * AT_STRIDE + bg * 4;
            const float* Wb = Wlds + (size_t)(128 + wave * 32) * 32 + jg * 4;
#pragma unroll 8
            for (int i = 0; i < 32; ++i) {
                float4 wv = *(const float4*)(Wb + i * 32);
                float2 a01 = *(const float2*)(Ab + i * AT_STRIDE);
                float2 a23 = *(const float2*)(Ab + i * AT_STRIDE + 2);
                float av[4] = {a01.x, a01.y, a23.x, a23.y};
                const float wj[4] = {wv.x, wv.y, wv.z, wv.w};
#pragma unroll
                for (int a_ = 0; a_ < 4; ++a_)
#pragma unroll
                    for (int b_ = 0; b_ < 4; ++b_)
                        acc[a_][b_] += wj[a_] * av[b_];
            }
        }

        qwait(cnt, q, ph);                    // wbuf ready (quarter-local)

        // -------- stage w-tile, B2: w-part GEMM (8 kk each of 128) ----------
        {
            int st16 = tid & 15, sbw = (tid >> 4) & 31, kh = tid >> 9;  // 0..1
            const float* wrow = wbuf + (size_t)(b0 + sbw) * IDIM;
            float4 w0 = cload4(wrow + (st16 + kh * 16) * 4);
            waitvm0();
            float* d0 = At4 + ((st16 + kh * 16) * 4) * AT_STRIDE + sbw;
            d0[0] = w0.x; d0[AT_STRIDE] = w0.y;
            d0[2 * AT_STRIDE] = w0.z; d0[3 * AT_STRIDE] = w0.w;
        }
        __syncthreads();
        {
            const float* Ab = At4 + (wave * 8) * AT_STRIDE + bg * 4;
            const float* Wb = Wlds + (size_t)(wave * 8) * 32 + jg * 4;
#pragma unroll
            for (int i = 0; i < 8; ++i) {
                float4 wv = *(const float4*)(Wb + i * 32);
                float2 a01 = *(const float2*)(Ab + i * AT_STRIDE);
                float2 a23 = *(const float2*)(Ab + i * AT_STRIDE + 2);
                float av[4] = {a01.x, a01.y, a23.x, a23.y};
                const float wj[4] = {wv.x, wv.y, wv.z, wv.w};
#pragma unroll
                for (int a_ = 0; a_ < 4; ++a_)
#pragma unroll
                    for (int b_ = 0; b_ < 4; ++b_)
                        acc[a_][b_] += wj[a_] * av[b_];
            }
        }

        // -------- two-stage 16->8->1 k-reduce (stride-33 + jg-rotation) -----
        float* red4 = At4 + AT_CH;            // chunks 1-2 region (dead)
        if (wave >= 8) {
#pragma unroll
            for (int ji = 0; ji < 4; ++ji) {
                int r = jg * 4 + ji;
#pragma unroll
                for (int eb = 0; eb < 4; ++eb)
                    red4[(wave - 8) * 1056 + r * 33 + bg * 4 + ((eb + jg) & 3)]
                        = acc[ji][eb];
            }
        }
        __syncthreads();
        if (wave < 8) {
#pragma unroll
            for (int ji = 0; ji < 4; ++ji) {
                int r = jg * 4 + ji;
#pragma unroll
                for (int eb = 0; eb < 4; ++eb)
                    red4[wave * 1056 + r * 33 + bg * 4 + ((eb + jg) & 3)]
                        += acc[ji][eb];
            }
        }
        __syncthreads();

        float* glds = At4;                    // chunk 0 (dead after B2)
        if (tid < 256) {
            int jj = tid >> 3, b8 = tid & 7;
            int rot = jj >> 2;
            float bias = blds[jj];
            float s[4] = {bias, bias, bias, bias};
#pragma unroll
            for (int w = 0; w < 8; ++w) {
                const float* rp = red4 + w * 1056 + jj * 33 + b8 * 4;
#pragma unroll
                for (int eb = 0; eb < 4; ++eb)
                    s[eb] += rp[(eb + rot) & 3];
            }
#pragma unroll
            for (int eb = 0; eb < 4; ++eb)
                glds[jj * 33 + b8 * 4 + eb] = s[eb];
        }
        __syncthreads();
        float hnew = 0.f;
        if (tid < 256) {
            int ub = tid >> 3, un = tid & 7;
            float ig = glds[(0 * 8 + un) * 33 + ub];
            float fg = glds[(1 * 8 + un) * 33 + ub];
            float gg = glds[(2 * 8 + un) * 33 + ub];
            float og = glds[(3 * 8 + un) * 33 + ub];
            int gb = b0 + ub, gn = n0 + un;
            float cnew = sigmoidf_(fg) * cown + sigmoidf_(ig) * tanhf(gg);
            hnew = sigmoidf_(og) * tanhf(cnew);
            cown = cnew;
            astore(cbuf + (size_t)gb * H + gn, cnew);
            astore(hbuf + (size_t)gb * H + gn, hnew);
        }

        // -------- ARRIVE #2 (h,c published); out-store under propagation ----
        ++ph;
        qarrive(cnt, q, ns, ph);
        if (tid < 256) {
            int gb = b0 + (tid >> 3), gn = n0 + (tid & 7);
            out[((size_t)gb * T + t) * H + gn] = hnew;
        }
        qwait(cnt, q, ph);                    // h_{t+1}, c_{t+1} ready
    }
}

// ---------------------------------------------------------------------------
extern "C" void kernel_launch(void* const* d_in, const int* in_sizes, int n_in,
                              void* d_out, int out_size, void* d_ws, size_t ws_size,
                              hipStream_t stream)
{
    const float* input  = (const float*)d_in[0];
    const float* news_W = (const float*)d_in[1];
    const float* news_b = (const float*)d_in[2];
    const float* A1     = (const float*)d_in[3];
    const float* b1     = (const float*)d_in[4];
    const float* A2     = (const float*)d_in[5];
    const float* b2     = (const float*)d_in[6];
    const float* a3w    = (const float*)d_in[7];
    // d_in[8] = attn3_b: softmax-invariant, unused
    const float* Wih    = (const float*)d_in[9];
    const float* Whh    = (const float*)d_in[10];
    const float* bih    = (const float*)d_in[11];
    const float* bhh    = (const float*)d_in[12];
    float* out = (float*)d_out;

    char* ws = (char*)d_ws;
    size_t off = 0;
    auto alloc = [&](size_t nelem) {
        float* p = (float*)(ws + off);
        off += ((nelem * 4 + 255) / 256) * 256;
        return p;
    };
    float* x    = alloc((size_t)B * T * IDIM);   // 4 MB
    float* z2   = alloc((size_t)B * IDIM * T);   // 4 MB
    float* wbuf = alloc((size_t)B * IDIM);       // 64 KB
    float* hbuf = alloc((size_t)B * H);          // single h buffer
    float* cbuf = alloc((size_t)B * H);          // single c buffer
    int*   cnt  = (int*)alloc(2048);             // barrier counters

    hipMemsetAsync(hbuf, 0, (size_t)B * H * 4, stream);
    hipMemsetAsync(cbuf, 0, (size_t)B * H * 4, stream);
    hipMemsetAsync(cnt, 0, 2048 * 4, stream);

    news_kernel<<<B * T * IDIM / 4, 256, 0, stream>>>(input, news_W, news_b, x);
    z2_kernel<<<B * IDIM, 64, 0, stream>>>(x, A2, b2, z2);
    scan_kernel<<<256, NT, 0, stream>>>(x, z2, A1, b1, a3w, Wih, Whh, bih, bhh,
                                        wbuf, hbuf, cbuf, cnt, out);
}

// Round 15
// 1172.052 us; speedup vs baseline: 1.2281x; 1.2281x over previous
//
#include <hip/hip_runtime.h>
#include <cstdint>
#include <cstddef>

#define B 128
#define T 64
#define IDIM 128
#define E 256
#define H 512
#define NT 512

#define AT_STRIDE 34
#define AT_CH (128 * AT_STRIDE)   // 4352 floats per 128-k chunk

// LDS pool offsets (floats)
#define OFF_W   0                       // Wlds[640][32] = 20480
#define OFF_A   20480                   // At4[4][AT_CH] = 17408
#define OFF_HC  (OFF_A + 4 * AT_CH)     // hc[1024]
#define OFF_Z1  (OFF_HC + 1024)        // z1s[64]
#define OFF_RED (OFF_Z1 + 64)          // red[128]
#define OFF_BI  (OFF_RED + 128)        // bias[32]
#define POOL_F  (OFF_BI + 32)          // 39136 floats = 156544 B (<160K)

__device__ __forceinline__ float waveReduceSum(float v) {
    for (int off = 32; off > 0; off >>= 1) v += __shfl_xor(v, off, 64);
    return v;
}

__device__ __forceinline__ float fast_tanh(float v) {
    float a = fabsf(v);
    float e = __expf(-2.f * a);
    float r = (1.f - e) * __builtin_amdgcn_rcpf(1.f + e);
    return copysignf(r, v);
}

__device__ __forceinline__ float sigmoidf_(float x) {
    return 1.0f / (1.0f + __expf(-x));
}

// Coherent scalar accessors (bypass stale L1/L2; served at coherence point).
__device__ __forceinline__ float aload(const float* p) {
    return __hip_atomic_load(p, __ATOMIC_RELAXED, __HIP_MEMORY_SCOPE_AGENT);
}
__device__ __forceinline__ void astore(float* p, float v) {
    __hip_atomic_store(p, v, __ATOMIC_RELAXED, __HIP_MEMORY_SCOPE_AGENT);
}
__device__ __forceinline__ int aload_i(const int* p) {
    return __hip_atomic_load(p, __ATOMIC_RELAXED, __HIP_MEMORY_SCOPE_AGENT);
}
__device__ __forceinline__ void astore_i(int* p, int v) {
    __hip_atomic_store(p, v, __ATOMIC_RELAXED, __HIP_MEMORY_SCOPE_AGENT);
}

// Coherent 16B load (async — must waitvm0() before using the result).
__device__ __forceinline__ float4 cload4(const float* p) {
    float4 v;
    asm volatile("global_load_dwordx4 %0, %1, off sc0 sc1" : "=v"(v) : "v"(p));
    return v;
}
__device__ __forceinline__ void waitvm0() {
    asm volatile("s_waitcnt vmcnt(0)" ::: "memory");
}

// ---------------------------------------------------------------------------
__global__ __launch_bounds__(256) void news_kernel(
    const float* __restrict__ in, const float* __restrict__ nW,
    const float* __restrict__ nb, float* __restrict__ x)
{
    int out_idx = blockIdx.x * 4 + (threadIdx.x >> 6);
    int lane = threadIdx.x & 63;
    const float4* src = (const float4*)(in + (size_t)out_idx * E);
    float4 a = src[lane];
    float4 wv = ((const float4*)nW)[lane];
    float s = a.x * wv.x + a.y * wv.y + a.z * wv.z + a.w * wv.w;
    s = waveReduceSum(s);
    if (lane == 0) x[out_idx] = s + nb[0];
}

// ---------------------------------------------------------------------------
__global__ __launch_bounds__(64) void z2_kernel(
    const float* __restrict__ x, const float* __restrict__ A2,
    const float* __restrict__ b2, float* __restrict__ z2)
{
    int b = blockIdx.x >> 7;
    int i = blockIdx.x & 127;
    int s = threadIdx.x;
    __shared__ float xs[T];
    xs[s] = x[((size_t)b * T + s) * IDIM + i];
    __syncthreads();
    float acc = b2[s];
    const float* arow = A2 + s * T;
#pragma unroll 8
    for (int tt = 0; tt < T; ++tt) acc += xs[tt] * arow[tt];
    z2[((size_t)b * IDIM + i) * T + s] = acc;
}

// ---------------------------------------------------------------------------
// Flag-array split barrier (per-quarter, 64 blocks). No atomics:
// arrive = one relaxed flag store (flag[bid], 64 B apart, monotonic phase);
// wait   = wave 7's 64 lanes poll all 64 flags in ONE coalesced round-trip
//          (__all over the wave). Removes the 8-way RMW serialization and
//          the dependent sub->root hop of the old two-level tree.
// Payload visibility: each wave drains its vmcnt at the arrive's
// __syncthreads (HIP barrier semantics), so all the block's global stores
// have completed before the flag store is issued — same argument as the
// verified RMW-tree qsync.
#define FLG_STRIDE 16   // 64 B between flags: no same-cacheline store serial.
__device__ __forceinline__ void qarrive(int* cnt, int bid, int ph) {
    __syncthreads();                     // all waves drain vmem before arrive
    if (threadIdx.x == NT - 1) {
        asm volatile("s_waitcnt vmcnt(0) lgkmcnt(0)" ::: "memory");
        astore_i(cnt + bid * FLG_STRIDE, ph);
    }
}
__device__ __forceinline__ void qwait(int* cnt, int q, int ph) {
    if (threadIdx.x >= NT - 64) {
        int lane = threadIdx.x & 63;
        const int* fp = cnt + (q * 64 + lane) * FLG_STRIDE;
        int spins = 0;
        while (!__all(aload_i(fp) >= ph)) {
            if (++spins > (1 << 16)) break;  // fail visibly, never hang
        }
    }
    __syncthreads();
}

// ---------------------------------------------------------------------------
// Persistent scan — verified R13 structure (512 thr, split barriers, R5
// tiling). R9/R10/R11 lesson: 128-VGPR cliff — do NOT extend live ranges
// across phases. R14 lesson: 1024-thread TLP regresses (sync-bound).
// This round's only change: the barrier mechanism (flag array, above).
__global__ __launch_bounds__(NT, 1) void scan_kernel(
    const float* __restrict__ x, const float* __restrict__ z2,
    const float* __restrict__ A1, const float* __restrict__ b1,
    const float* __restrict__ a3w,
    const float* __restrict__ Wih, const float* __restrict__ Whh,
    const float* __restrict__ bih, const float* __restrict__ bhh,
    float* __restrict__ wbuf, float* __restrict__ hbuf, float* __restrict__ cbuf,
    int* __restrict__ cnt, float* __restrict__ out)
{
    __shared__ float pool[POOL_F];
    float* Wlds = pool + OFF_W;
    float* At4  = pool + OFF_A;
    float* hcs  = pool + OFF_HC;
    float* z1s  = pool + OFF_Z1;
    float* redl = pool + OFF_RED;
    float* blds = pool + OFF_BI;

    const int tid  = threadIdx.x;
    const int bid  = blockIdx.x;
    const int lane = tid & 63, wave = tid >> 6;
    const int q = bid >> 6, ns = bid & 63;
    const int b0 = q * 32, n0 = ns * 8;
    const int ab = b0 + (ns >> 1);             // attn batch (pair-shared)
    const int par = ns & 1;                    // which wbuf half to write
    const int jg = lane & 7, bg = lane >> 3;   // compute tile coords
    const int half = tid >> 8;                 // h-staging: 2 halves x 2 chunks
    const int sbh = (tid & 255) >> 3;          // batch row 0..31
    const int st8 = tid & 7;

    // one-time: weight slice (cols j = g*512 + n0 + nn; 4 gates x 8 n)
    for (int idx = tid; idx < 640 * 32; idx += NT) {
        int jj = idx / 640, k = idx - jj * 640;
        int j = (jj >> 3) * 512 + n0 + (jj & 7);
        Wlds[k * 32 + jj] = (k < 128) ? Wih[(size_t)j * 128 + k]
                                      : Whh[(size_t)j * 512 + (k - 128)];
    }
    if (tid < 32) {
        int j = (tid >> 3) * 512 + n0 + (tid & 7);
        blds[tid] = bih[j] + bhh[j];
    }

    // block-local cell state: thread tid<256 owns c[b0 + (tid>>3)][n0 + (tid&7)]
    float cown = 0.f;

    int ph = 0;
    for (int t = 0; t < T; ++t) {
        // -------- issue coherent h-tile prefetch (latency hides under attn)
        float4 hv[8];
        {
            const float* hrow = hbuf + (size_t)(b0 + sbh) * H + half * 256;
#pragma unroll
            for (int cc = 0; cc < 2; ++cc)
#pragma unroll
                for (int qq = 0; qq < 4; ++qq)
                    hv[cc * 4 + qq] = cload4(hrow + cc * 128 + (st8 + 8 * qq) * 4);
        }

        // -------- phase A: attention (ALL blocks; pair-duplicated) ----------
        {
            hcs[tid]     = aload(hbuf + (size_t)ab * H + tid);
            hcs[H + tid] = aload(cbuf + (size_t)ab * H + tid);
            __syncthreads();
            // z1: scalar stride-64 LDS reads (2-way, conflict-free)
            for (int r = 0; r < 8; ++r) {
                int tt = r * 8 + wave;
                const float* row = A1 + (size_t)tt * (2 * H);
                float p = 0.f;
#pragma unroll
                for (int qq = 0; qq < 16; ++qq)
                    p += row[lane + qq * 64] * hcs[lane + qq * 64];
                p = waveReduceSum(p);
                if (lane == 0) z1s[tt] = p + b1[tt];
            }
            __syncthreads();
            int i = tid >> 2, qt = tid & 3;
            const float* z2r = z2 + ((size_t)ab * IDIM + i) * T + qt * 16;
            const float* z1p = z1s + qt * 16;
            const float* a3p = a3w + qt * 16;
            float accz = 0.f;
#pragma unroll
            for (int qq = 0; qq < 4; ++qq) {
                float4 zv  = *(const float4*)(z2r + qq * 4);
                float4 z1v = *(const float4*)(z1p + qq * 4);
                float4 a3v = *(const float4*)(a3p + qq * 4);
                accz += fast_tanh(z1v.x + zv.x) * a3v.x
                      + fast_tanh(z1v.y + zv.y) * a3v.y
                      + fast_tanh(z1v.z + zv.z) * a3v.z
                      + fast_tanh(z1v.w + zv.w) * a3v.w;
            }
            accz += __shfl_xor(accz, 1, 64);
            accz += __shfl_xor(accz, 2, 64);
            if (qt == 0) redl[i] = accz;
            __syncthreads();
            if (wave == 0) {
                float v0 = redl[lane], v1 = redl[lane + 64];
                float m = fmaxf(v0, v1);
                for (int off = 32; off > 0; off >>= 1)
                    m = fmaxf(m, __shfl_xor(m, off, 64));
                float e0 = __expf(v0 - m), e1 = __expf(v1 - m);
                float inv = 1.0f / waveReduceSum(e0 + e1);
                const float* xt = x + ((size_t)ab * T + t) * IDIM;
                if (par == 0)
                    astore(wbuf + ab * IDIM + lane,      e0 * inv * xt[lane]);
                else
                    astore(wbuf + ab * IDIM + lane + 64, e1 * inv * xt[lane + 64]);
            }
        }

        // -------- ARRIVE #1 (wbuf published); flags settle under B1 ---------
        ++ph;
        qarrive(cnt, bid, ph);

        // -------- stage h-tile into LDS (transposed, stride-34) -------------
        waitvm0();
        {
#pragma unroll
            for (int cc = 0; cc < 2; ++cc)
#pragma unroll
                for (int qq = 0; qq < 4; ++qq) {
                    float4 v = hv[cc * 4 + qq];
                    float* d = At4 + (half * 2 + cc) * AT_CH
                             + ((st8 + 8 * qq) * 4) * AT_STRIDE + sbh;
                    d[0] = v.x; d[AT_STRIDE] = v.y;
                    d[2 * AT_STRIDE] = v.z; d[3 * AT_STRIDE] = v.w;
                }
        }
        __syncthreads();

        // -------- B1: h-part GEMM, wave k-split (64 kk each of 512) ---------
        float acc[4][4];   // [ji (j within group)][eb (b within group)]
#pragma unroll
        for (int a_ = 0; a_ < 4; ++a_)
#pragma unroll
            for (int b_ = 0; b_ < 4; ++b_) acc[a_][b_] = 0.f;
        {
            const float* Ab = At4 + (wave >> 1) * AT_CH
                            + ((wave & 1) * 64) * AT_STRIDE + bg * 4;
            const float* Wb = Wlds + (size_t)(128 + wave * 64) * 32 + jg * 4;
#pragma unroll 8
            for (int i = 0; i < 64; ++i) {
                float4 wv = *(const float4*)(Wb + i * 32);
                float2 a01 = *(const float2*)(Ab + i * AT_STRIDE);
                float2 a23 = *(const float2*)(Ab + i * AT_STRIDE + 2);
                float av[4] = {a01.x, a01.y, a23.x, a23.y};
                const float wj[4] = {wv.x, wv.y, wv.z, wv.w};
#pragma unroll
                for (int a_ = 0; a_ < 4; ++a_)
#pragma unroll
                    for (int b_ = 0; b_ < 4; ++b_)
                        acc[a_][b_] += wj[a_] * av[b_];
            }
        }

        qwait(cnt, q, ph);                    // wbuf ready (quarter-local)

        // -------- stage w-tile, B2: w-part GEMM (16 kk each of 128) ---------
        {
            const float* wrow = wbuf + (size_t)(b0 + (tid >> 4)) * IDIM;
            float4 w0 = cload4(wrow + (tid & 15) * 4);
            float4 w1 = cload4(wrow + ((tid & 15) + 16) * 4);
            waitvm0();
            int sbw = tid >> 4, st16 = tid & 15;
            float* d0 = At4 + (st16 * 4) * AT_STRIDE + sbw;
            d0[0] = w0.x; d0[AT_STRIDE] = w0.y;
            d0[2 * AT_STRIDE] = w0.z; d0[3 * AT_STRIDE] = w0.w;
            float* d1 = At4 + ((st16 + 16) * 4) * AT_STRIDE + sbw;
            d1[0] = w1.x; d1[AT_STRIDE] = w1.y;
            d1[2 * AT_STRIDE] = w1.z; d1[3 * AT_STRIDE] = w1.w;
        }
        __syncthreads();
        {
            const float* Ab = At4 + (wave * 16) * AT_STRIDE + bg * 4;
            const float* Wb = Wlds + (size_t)(wave * 16) * 32 + jg * 4;
#pragma unroll
            for (int i = 0; i < 16; ++i) {
                float4 wv = *(const float4*)(Wb + i * 32);
                float2 a01 = *(const float2*)(Ab + i * AT_STRIDE);
                float2 a23 = *(const float2*)(Ab + i * AT_STRIDE + 2);
                float av[4] = {a01.x, a01.y, a23.x, a23.y};
                const float wj[4] = {wv.x, wv.y, wv.z, wv.w};
#pragma unroll
                for (int a_ = 0; a_ < 4; ++a_)
#pragma unroll
                    for (int b_ = 0; b_ < 4; ++b_)
                        acc[a_][b_] += wj[a_] * av[b_];
            }
        }

        // -------- 8-way cross-wave k-reduce (stride-33 + jg-rotation) -------
        float* red4 = At4 + AT_CH;            // 8448 floats, chunks 1-2 (dead)
#pragma unroll
        for (int ji = 0; ji < 4; ++ji) {
            int r = jg * 4 + ji;
#pragma unroll
            for (int eb = 0; eb < 4; ++eb)
                red4[wave * 1056 + r * 33 + bg * 4 + ((eb + jg) & 3)] = acc[ji][eb];
        }
        __syncthreads();

        float* glds = At4;                    // chunk 0 (dead after B2)
        if (tid < 256) {
            int jj = tid >> 3, b8 = tid & 7;
            int rot = jj >> 2;
            float bias = blds[jj];
            float s[4] = {bias, bias, bias, bias};
#pragma unroll
            for (int w = 0; w < 8; ++w) {
                const float* rp = red4 + w * 1056 + jj * 33 + b8 * 4;
#pragma unroll
                for (int eb = 0; eb < 4; ++eb)
                    s[eb] += rp[(eb + rot) & 3];
            }
#pragma unroll
            for (int eb = 0; eb < 4; ++eb)
                glds[jj * 33 + b8 * 4 + eb] = s[eb];
        }
        __syncthreads();
        float hnew = 0.f;
        if (tid < 256) {
            int ub = tid >> 3, un = tid & 7;
            float ig = glds[(0 * 8 + un) * 33 + ub];
            float fg = glds[(1 * 8 + un) * 33 + ub];
            float gg = glds[(2 * 8 + un) * 33 + ub];
            float og = glds[(3 * 8 + un) * 33 + ub];
            int gb = b0 + ub, gn = n0 + un;
            float cnew = sigmoidf_(fg) * cown + sigmoidf_(ig) * tanhf(gg);
            hnew = sigmoidf_(og) * tanhf(cnew);
            cown = cnew;
            astore(cbuf + (size_t)gb * H + gn, cnew);
            astore(hbuf + (size_t)gb * H + gn, hnew);
        }

        // -------- ARRIVE #2 (h,c published); out-store under settle ---------
        ++ph;
        qarrive(cnt, bid, ph);
        if (tid < 256) {
            int gb = b0 + (tid >> 3), gn = n0 + (tid & 7);
            out[((size_t)gb * T + t) * H + gn] = hnew;
        }
        qwait(cnt, q, ph);                    // h_{t+1}, c_{t+1} ready
    }
}

// ---------------------------------------------------------------------------
extern "C" void kernel_launch(void* const* d_in, const int* in_sizes, int n_in,
                              void* d_out, int out_size, void* d_ws, size_t ws_size,
                              hipStream_t stream)
{
    const float* input  = (const float*)d_in[0];
    const float* news_W = (const float*)d_in[1];
    const float* news_b = (const float*)d_in[2];
    const float* A1     = (const float*)d_in[3];
    const float* b1     = (const float*)d_in[4];
    const float* A2     = (const float*)d_in[5];
    const float* b2     = (const float*)d_in[6];
    const float* a3w    = (const float*)d_in[7];
    // d_in[8] = attn3_b: softmax-invariant, unused
    const float* Wih    = (const float*)d_in[9];
    const float* Whh    = (const float*)d_in[10];
    const float* bih    = (const float*)d_in[11];
    const float* bhh    = (const float*)d_in[12];
    float* out = (float*)d_out;

    char* ws = (char*)d_ws;
    size_t off = 0;
    auto alloc = [&](size_t nelem) {
        float* p = (float*)(ws + off);
        off += ((nelem * 4 + 255) / 256) * 256;
        return p;
    };
    float* x    = alloc((size_t)B * T * IDIM);   // 4 MB
    float* z2   = alloc((size_t)B * IDIM * T);   // 4 MB
    float* wbuf = alloc((size_t)B * IDIM);       // 64 KB
    float* hbuf = alloc((size_t)B * H);          // single h buffer
    float* cbuf = alloc((size_t)B * H);          // single c buffer
    int*   cnt  = (int*)alloc(4096);             // 256 flags x 16-int stride

    hipMemsetAsync(hbuf, 0, (size_t)B * H * 4, stream);
    hipMemsetAsync(cbuf, 0, (size_t)B * H * 4, stream);
    hipMemsetAsync(cnt, 0, 4096 * 4, stream);

    news_kernel<<<B * T * IDIM / 4, 256, 0, stream>>>(input, news_W, news_b, x);
    z2_kernel<<<B * IDIM, 64, 0, stream>>>(x, A2, b2, z2);
    scan_kernel<<<256, NT, 0, stream>>>(x, z2, A1, b1, a3w, Wih, Whh, bih, bhh,
                                        wbuf, hbuf, cbuf, cnt, out);
}

// Round 16
// 1169.438 us; speedup vs baseline: 1.2309x; 1.0022x over previous
//
#include <hip/hip_runtime.h>
#include <cstdint>
#include <cstddef>

#define B 128
#define T 64
#define IDIM 128
#define E 256
#define H 512
#define NT 512

#define AT_STRIDE 34
#define AT_CH (128 * AT_STRIDE)   // 4352 floats per 128-k chunk

// LDS pool offsets (floats)
#define OFF_W   0                       // Wlds[640][32] = 20480
#define OFF_A   20480                   // At4[4][AT_CH] = 17408
#define OFF_HC  (OFF_A + 4 * AT_CH)     // hc[1024]
#define OFF_Z1  (OFF_HC + 1024)        // z1s[64]
#define OFF_RED (OFF_Z1 + 64)          // red[128]
#define OFF_BI  (OFF_RED + 128)        // bias[32]
#define POOL_F  (OFF_BI + 32)          // 39136 floats = 156544 B (<160K)

__device__ __forceinline__ float waveReduceSum(float v) {
    for (int off = 32; off > 0; off >>= 1) v += __shfl_xor(v, off, 64);
    return v;
}

__device__ __forceinline__ float fast_tanh(float v) {
    float a = fabsf(v);
    float e = __expf(-2.f * a);
    float r = (1.f - e) * __builtin_amdgcn_rcpf(1.f + e);
    return copysignf(r, v);
}

__device__ __forceinline__ float sigmoidf_(float x) {
    return 1.0f / (1.0f + __expf(-x));
}

// Coherent scalar accessors (bypass stale L1/L2; served at coherence point).
__device__ __forceinline__ float aload(const float* p) {
    return __hip_atomic_load(p, __ATOMIC_RELAXED, __HIP_MEMORY_SCOPE_AGENT);
}
__device__ __forceinline__ void astore(float* p, float v) {
    __hip_atomic_store(p, v, __ATOMIC_RELAXED, __HIP_MEMORY_SCOPE_AGENT);
}
__device__ __forceinline__ int aload_i(const int* p) {
    return __hip_atomic_load(p, __ATOMIC_RELAXED, __HIP_MEMORY_SCOPE_AGENT);
}
__device__ __forceinline__ void astore_i(int* p, int v) {
    __hip_atomic_store(p, v, __ATOMIC_RELAXED, __HIP_MEMORY_SCOPE_AGENT);
}

// Coherent 16B load (async — must waitvm0() before using the result).
__device__ __forceinline__ float4 cload4(const float* p) {
    float4 v;
    asm volatile("global_load_dwordx4 %0, %1, off sc0 sc1" : "=v"(v) : "v"(p));
    return v;
}
__device__ __forceinline__ void waitvm0() {
    asm volatile("s_waitcnt vmcnt(0)" ::: "memory");
}

// ---------------------------------------------------------------------------
__global__ __launch_bounds__(256) void news_kernel(
    const float* __restrict__ in, const float* __restrict__ nW,
    const float* __restrict__ nb, float* __restrict__ x)
{
    int out_idx = blockIdx.x * 4 + (threadIdx.x >> 6);
    int lane = threadIdx.x & 63;
    const float4* src = (const float4*)(in + (size_t)out_idx * E);
    float4 a = src[lane];
    float4 wv = ((const float4*)nW)[lane];
    float s = a.x * wv.x + a.y * wv.y + a.z * wv.z + a.w * wv.w;
    s = waveReduceSum(s);
    if (lane == 0) x[out_idx] = s + nb[0];
}

// ---------------------------------------------------------------------------
__global__ __launch_bounds__(64) void z2_kernel(
    const float* __restrict__ x, const float* __restrict__ A2,
    const float* __restrict__ b2, float* __restrict__ z2)
{
    int b = blockIdx.x >> 7;
    int i = blockIdx.x & 127;
    int s = threadIdx.x;
    __shared__ float xs[T];
    xs[s] = x[((size_t)b * T + s) * IDIM + i];
    __syncthreads();
    float acc = b2[s];
    const float* arow = A2 + s * T;
#pragma unroll 8
    for (int tt = 0; tt < T; ++tt) acc += xs[tt] * arow[tt];
    z2[((size_t)b * IDIM + i) * T + s] = acc;
}

// ---------------------------------------------------------------------------
// Flag-array split barrier (per-quarter, 64 blocks). No atomics:
// arrive = one relaxed flag store (flag[bid], 64 B apart, monotonic phase);
// wait   = wave 7's 64 lanes poll all 64 flags in ONE coalesced round-trip.
// Payload visibility: each wave drains vmcnt at the arrive's __syncthreads,
// so the block's global stores complete before the flag store is issued.
#define FLG_STRIDE 16   // 64 B between flags: no same-cacheline store serial.
__device__ __forceinline__ void qarrive(int* cnt, int bid, int ph) {
    __syncthreads();                     // all waves drain vmem before arrive
    if (threadIdx.x == NT - 1) {
        asm volatile("s_waitcnt vmcnt(0) lgkmcnt(0)" ::: "memory");
        astore_i(cnt + bid * FLG_STRIDE, ph);
    }
}
__device__ __forceinline__ void qwait(int* cnt, int q, int ph) {
    if (threadIdx.x >= NT - 64) {
        int lane = threadIdx.x & 63;
        const int* fp = cnt + (q * 64 + lane) * FLG_STRIDE;
        int spins = 0;
        while (!__all(aload_i(fp) >= ph)) {
            if (++spins > (1 << 16)) break;  // fail visibly, never hang
        }
    }
    __syncthreads();
}

// ---------------------------------------------------------------------------
// Persistent scan — R15 chassis (512 thr, flag-array split barriers, R5
// tiling) with DE-DUPLICATED attention: only even-ns blocks run attn (one
// block per batch), computing the full z3 and writing both wbuf halves
// (R4's verified indexing). Odd blocks arrive at barrier #1 immediately and
// proceed to stage+B1 — the split barrier absorbs the asymmetry. Halves the
// per-XCD A1 L2 streaming (8 -> 4 MB/step), which floor-bounded z1.
// VGPR-cliff rule (R9/R10/R11): no live ranges extended across phases.
__global__ __launch_bounds__(NT, 1) void scan_kernel(
    const float* __restrict__ x, const float* __restrict__ z2,
    const float* __restrict__ A1, const float* __restrict__ b1,
    const float* __restrict__ a3w,
    const float* __restrict__ Wih, const float* __restrict__ Whh,
    const float* __restrict__ bih, const float* __restrict__ bhh,
    float* __restrict__ wbuf, float* __restrict__ hbuf, float* __restrict__ cbuf,
    int* __restrict__ cnt, float* __restrict__ out)
{
    __shared__ float pool[POOL_F];
    float* Wlds = pool + OFF_W;
    float* At4  = pool + OFF_A;
    float* hcs  = pool + OFF_HC;
    float* z1s  = pool + OFF_Z1;
    float* redl = pool + OFF_RED;
    float* blds = pool + OFF_BI;

    const int tid  = threadIdx.x;
    const int bid  = blockIdx.x;
    const int lane = tid & 63, wave = tid >> 6;
    const int q = bid >> 6, ns = bid & 63;
    const int b0 = q * 32, n0 = ns * 8;
    const int ab = b0 + (ns >> 1);             // attn batch
    const bool is_attn = ((ns & 1) == 0);      // one attn block per batch
    const int jg = lane & 7, bg = lane >> 3;   // compute tile coords
    const int half = tid >> 8;                 // h-staging: 2 halves x 2 chunks
    const int sbh = (tid & 255) >> 3;          // batch row 0..31
    const int st8 = tid & 7;

    // one-time: weight slice (cols j = g*512 + n0 + nn; 4 gates x 8 n)
    for (int idx = tid; idx < 640 * 32; idx += NT) {
        int jj = idx / 640, k = idx - jj * 640;
        int j = (jj >> 3) * 512 + n0 + (jj & 7);
        Wlds[k * 32 + jj] = (k < 128) ? Wih[(size_t)j * 128 + k]
                                      : Whh[(size_t)j * 512 + (k - 128)];
    }
    if (tid < 32) {
        int j = (tid >> 3) * 512 + n0 + (tid & 7);
        blds[tid] = bih[j] + bhh[j];
    }

    // block-local cell state: thread tid<256 owns c[b0 + (tid>>3)][n0 + (tid&7)]
    float cown = 0.f;

    int ph = 0;
    for (int t = 0; t < T; ++t) {
        // -------- issue coherent h-tile prefetch (latency hides under attn)
        float4 hv[8];
        {
            const float* hrow = hbuf + (size_t)(b0 + sbh) * H + half * 256;
#pragma unroll
            for (int cc = 0; cc < 2; ++cc)
#pragma unroll
                for (int qq = 0; qq < 4; ++qq)
                    hv[cc * 4 + qq] = cload4(hrow + cc * 128 + (st8 + 8 * qq) * 4);
        }

        // -------- phase A: attention (EVEN blocks only; full batch) ---------
        if (is_attn) {
            hcs[tid]     = aload(hbuf + (size_t)ab * H + tid);
            hcs[H + tid] = aload(cbuf + (size_t)ab * H + tid);
            __syncthreads();
            // z1: scalar stride-64 LDS reads (2-way, conflict-free)
            for (int r = 0; r < 8; ++r) {
                int tt = r * 8 + wave;
                const float* row = A1 + (size_t)tt * (2 * H);
                float p = 0.f;
#pragma unroll
                for (int qq = 0; qq < 16; ++qq)
                    p += row[lane + qq * 64] * hcs[lane + qq * 64];
                p = waveReduceSum(p);
                if (lane == 0) z1s[tt] = p + b1[tt];
            }
            __syncthreads();
            // z3: 4 threads per driver row, 16 t each (R4-verified indexing)
            int i = tid >> 2, qt = tid & 3;
            const float* z2r = z2 + ((size_t)ab * IDIM + i) * T + qt * 16;
            const float* z1p = z1s + qt * 16;
            const float* a3p = a3w + qt * 16;
            float accz = 0.f;
#pragma unroll
            for (int qq = 0; qq < 4; ++qq) {
                float4 zv  = *(const float4*)(z2r + qq * 4);
                float4 z1v = *(const float4*)(z1p + qq * 4);
                float4 a3v = *(const float4*)(a3p + qq * 4);
                accz += fast_tanh(z1v.x + zv.x) * a3v.x
                      + fast_tanh(z1v.y + zv.y) * a3v.y
                      + fast_tanh(z1v.z + zv.z) * a3v.z
                      + fast_tanh(z1v.w + zv.w) * a3v.w;
            }
            accz += __shfl_xor(accz, 1, 64);
            accz += __shfl_xor(accz, 2, 64);
            if (qt == 0) redl[i] = accz;
            __syncthreads();
            if (wave == 0) {
                float v0 = redl[lane], v1 = redl[lane + 64];
                float m = fmaxf(v0, v1);
                for (int off = 32; off > 0; off >>= 1)
                    m = fmaxf(m, __shfl_xor(m, off, 64));
                float e0 = __expf(v0 - m), e1 = __expf(v1 - m);
                float inv = 1.0f / waveReduceSum(e0 + e1);
                const float* xt = x + ((size_t)ab * T + t) * IDIM;
                astore(wbuf + ab * IDIM + lane,      e0 * inv * xt[lane]);
                astore(wbuf + ab * IDIM + lane + 64, e1 * inv * xt[lane + 64]);
            }
        }

        // -------- ARRIVE #1 (wbuf published); flags settle under B1 ---------
        ++ph;
        qarrive(cnt, bid, ph);

        // -------- stage h-tile into LDS (transposed, stride-34) -------------
        waitvm0();
        {
#pragma unroll
            for (int cc = 0; cc < 2; ++cc)
#pragma unroll
                for (int qq = 0; qq < 4; ++qq) {
                    float4 v = hv[cc * 4 + qq];
                    float* d = At4 + (half * 2 + cc) * AT_CH
                             + ((st8 + 8 * qq) * 4) * AT_STRIDE + sbh;
                    d[0] = v.x; d[AT_STRIDE] = v.y;
                    d[2 * AT_STRIDE] = v.z; d[3 * AT_STRIDE] = v.w;
                }
        }
        __syncthreads();

        // -------- B1: h-part GEMM, wave k-split (64 kk each of 512) ---------
        float acc[4][4];   // [ji (j within group)][eb (b within group)]
#pragma unroll
        for (int a_ = 0; a_ < 4; ++a_)
#pragma unroll
            for (int b_ = 0; b_ < 4; ++b_) acc[a_][b_] = 0.f;
        {
            const float* Ab = At4 + (wave >> 1) * AT_CH
                            + ((wave & 1) * 64) * AT_STRIDE + bg * 4;
            const float* Wb = Wlds + (size_t)(128 + wave * 64) * 32 + jg * 4;
#pragma unroll 8
            for (int i = 0; i < 64; ++i) {
                float4 wv = *(const float4*)(Wb + i * 32);
                float2 a01 = *(const float2*)(Ab + i * AT_STRIDE);
                float2 a23 = *(const float2*)(Ab + i * AT_STRIDE + 2);
                float av[4] = {a01.x, a01.y, a23.x, a23.y};
                const float wj[4] = {wv.x, wv.y, wv.z, wv.w};
#pragma unroll
                for (int a_ = 0; a_ < 4; ++a_)
#pragma unroll
                    for (int b_ = 0; b_ < 4; ++b_)
                        acc[a_][b_] += wj[a_] * av[b_];
            }
        }

        qwait(cnt, q, ph);                    // wbuf ready (quarter-local)

        // -------- stage w-tile, B2: w-part GEMM (16 kk each of 128) ---------
        {
            const float* wrow = wbuf + (size_t)(b0 + (tid >> 4)) * IDIM;
            float4 w0 = cload4(wrow + (tid & 15) * 4);
            float4 w1 = cload4(wrow + ((tid & 15) + 16) * 4);
            waitvm0();
            int sbw = tid >> 4, st16 = tid & 15;
            float* d0 = At4 + (st16 * 4) * AT_STRIDE + sbw;
            d0[0] = w0.x; d0[AT_STRIDE] = w0.y;
            d0[2 * AT_STRIDE] = w0.z; d0[3 * AT_STRIDE] = w0.w;
            float* d1 = At4 + ((st16 + 16) * 4) * AT_STRIDE + sbw;
            d1[0] = w1.x; d1[AT_STRIDE] = w1.y;
            d1[2 * AT_STRIDE] = w1.z; d1[3 * AT_STRIDE] = w1.w;
        }
        __syncthreads();
        {
            const float* Ab = At4 + (wave * 16) * AT_STRIDE + bg * 4;
            const float* Wb = Wlds + (size_t)(wave * 16) * 32 + jg * 4;
#pragma unroll
            for (int i = 0; i < 16; ++i) {
                float4 wv = *(const float4*)(Wb + i * 32);
                float2 a01 = *(const float2*)(Ab + i * AT_STRIDE);
                float2 a23 = *(const float2*)(Ab + i * AT_STRIDE + 2);
                float av[4] = {a01.x, a01.y, a23.x, a23.y};
                const float wj[4] = {wv.x, wv.y, wv.z, wv.w};
#pragma unroll
                for (int a_ = 0; a_ < 4; ++a_)
#pragma unroll
                    for (int b_ = 0; b_ < 4; ++b_)
                        acc[a_][b_] += wj[a_] * av[b_];
            }
        }

        // -------- 8-way cross-wave k-reduce (stride-33 + jg-rotation) -------
        float* red4 = At4 + AT_CH;            // 8448 floats, chunks 1-2 (dead)
#pragma unroll
        for (int ji = 0; ji < 4; ++ji) {
            int r = jg * 4 + ji;
#pragma unroll
            for (int eb = 0; eb < 4; ++eb)
                red4[wave * 1056 + r * 33 + bg * 4 + ((eb + jg) & 3)] = acc[ji][eb];
        }
        __syncthreads();

        float* glds = At4;                    // chunk 0 (dead after B2)
        if (tid < 256) {
            int jj = tid >> 3, b8 = tid & 7;
            int rot = jj >> 2;
            float bias = blds[jj];
            float s[4] = {bias, bias, bias, bias};
#pragma unroll
            for (int w = 0; w < 8; ++w) {
                const float* rp = red4 + w * 1056 + jj * 33 + b8 * 4;
#pragma unroll
                for (int eb = 0; eb < 4; ++eb)
                    s[eb] += rp[(eb + rot) & 3];
            }
#pragma unroll
            for (int eb = 0; eb < 4; ++eb)
                glds[jj * 33 + b8 * 4 + eb] = s[eb];
        }
        __syncthreads();
        float hnew = 0.f;
        if (tid < 256) {
            int ub = tid >> 3, un = tid & 7;
            float ig = glds[(0 * 8 + un) * 33 + ub];
            float fg = glds[(1 * 8 + un) * 33 + ub];
            float gg = glds[(2 * 8 + un) * 33 + ub];
            float og = glds[(3 * 8 + un) * 33 + ub];
            int gb = b0 + ub, gn = n0 + un;
            float cnew = sigmoidf_(fg) * cown + sigmoidf_(ig) * tanhf(gg);
            hnew = sigmoidf_(og) * tanhf(cnew);
            cown = cnew;
            astore(cbuf + (size_t)gb * H + gn, cnew);
            astore(hbuf + (size_t)gb * H + gn, hnew);
        }

        // -------- ARRIVE #2 (h,c published); out-store under settle ---------
        ++ph;
        qarrive(cnt, bid, ph);
        if (tid < 256) {
            int gb = b0 + (tid >> 3), gn = n0 + (tid & 7);
            out[((size_t)gb * T + t) * H + gn] = hnew;
        }
        qwait(cnt, q, ph);                    // h_{t+1}, c_{t+1} ready
    }
}

// ---------------------------------------------------------------------------
extern "C" void kernel_launch(void* const* d_in, const int* in_sizes, int n_in,
                              void* d_out, int out_size, void* d_ws, size_t ws_size,
                              hipStream_t stream)
{
    const float* input  = (const float*)d_in[0];
    const float* news_W = (const float*)d_in[1];
    const float* news_b = (const float*)d_in[2];
    const float* A1     = (const float*)d_in[3];
    const float* b1     = (const float*)d_in[4];
    const float* A2     = (const float*)d_in[5];
    const float* b2     = (const float*)d_in[6];
    const float* a3w    = (const float*)d_in[7];
    // d_in[8] = attn3_b: softmax-invariant, unused
    const float* Wih    = (const float*)d_in[9];
    const float* Whh    = (const float*)d_in[10];
    const float* bih    = (const float*)d_in[11];
    const float* bhh    = (const float*)d_in[12];
    float* out = (float*)d_out;

    char* ws = (char*)d_ws;
    size_t off = 0;
    auto alloc = [&](size_t nelem) {
        float* p = (float*)(ws + off);
        off += ((nelem * 4 + 255) / 256) * 256;
        return p;
    };
    float* x    = alloc((size_t)B * T * IDIM);   // 4 MB
    float* z2   = alloc((size_t)B * IDIM * T);   // 4 MB
    float* wbuf = alloc((size_t)B * IDIM);       // 64 KB
    float* hbuf = alloc((size_t)B * H);          // single h buffer
    float* cbuf = alloc((size_t)B * H);          // single c buffer
    int*   cnt  = (int*)alloc(4096);             // 256 flags x 16-int stride

    hipMemsetAsync(hbuf, 0, (size_t)B * H * 4, stream);
    hipMemsetAsync(cbuf, 0, (size_t)B * H * 4, stream);
    hipMemsetAsync(cnt, 0, 4096 * 4, stream);

    news_kernel<<<B * T * IDIM / 4, 256, 0, stream>>>(input, news_W, news_b, x);
    z2_kernel<<<B * IDIM, 64, 0, stream>>>(x, A2, b2, z2);
    scan_kernel<<<256, NT, 0, stream>>>(x, z2, A1, b1, a3w, Wih, Whh, bih, bhh,
                                        wbuf, hbuf, cbuf, cnt, out);
}

// Round 17
// 1161.578 us; speedup vs baseline: 1.2392x; 1.0068x over previous
//
#include <hip/hip_runtime.h>
#include <cstdint>
#include <cstddef>

#define B 128
#define T 64
#define IDIM 128
#define E 256
#define H 512
#define NT 512

#define AT_STRIDE 34
#define AT_CH (128 * AT_STRIDE)   // 4352 floats per 128-k chunk

// LDS pool offsets (floats)
#define OFF_W   0                       // Wlds[640][32] = 20480
#define OFF_A   20480                   // At4[4][AT_CH] = 17408
#define OFF_HC  (OFF_A + 4 * AT_CH)     // hc[1024]
#define OFF_Z1  (OFF_HC + 1024)        // z1s[64]
#define OFF_RED (OFF_Z1 + 64)          // red[128]
#define OFF_BI  (OFF_RED + 128)        // bias[32]
#define POOL_F  (OFF_BI + 32)          // 39136 floats = 156544 B (<160K)

__device__ __forceinline__ float waveReduceSum(float v) {
    for (int off = 32; off > 0; off >>= 1) v += __shfl_xor(v, off, 64);
    return v;
}

__device__ __forceinline__ float fast_tanh(float v) {
    float a = fabsf(v);
    float e = __expf(-2.f * a);
    float r = (1.f - e) * __builtin_amdgcn_rcpf(1.f + e);
    return copysignf(r, v);
}

__device__ __forceinline__ float sigmoidf_(float x) {
    return 1.0f / (1.0f + __expf(-x));
}

// Coherent scalar accessors (bypass stale L1/L2; served at coherence point).
__device__ __forceinline__ float aload(const float* p) {
    return __hip_atomic_load(p, __ATOMIC_RELAXED, __HIP_MEMORY_SCOPE_AGENT);
}
__device__ __forceinline__ void astore(float* p, float v) {
    __hip_atomic_store(p, v, __ATOMIC_RELAXED, __HIP_MEMORY_SCOPE_AGENT);
}
__device__ __forceinline__ int aload_i(const int* p) {
    return __hip_atomic_load(p, __ATOMIC_RELAXED, __HIP_MEMORY_SCOPE_AGENT);
}
__device__ __forceinline__ void astore_i(int* p, int v) {
    __hip_atomic_store(p, v, __ATOMIC_RELAXED, __HIP_MEMORY_SCOPE_AGENT);
}

// Coherent 16B load (async — must waitvm0() before using the result).
__device__ __forceinline__ float4 cload4(const float* p) {
    float4 v;
    asm volatile("global_load_dwordx4 %0, %1, off sc0 sc1" : "=v"(v) : "v"(p));
    return v;
}
__device__ __forceinline__ void waitvm0() {
    asm volatile("s_waitcnt vmcnt(0)" ::: "memory");
}

// ---------------------------------------------------------------------------
__global__ __launch_bounds__(256) void news_kernel(
    const float* __restrict__ in, const float* __restrict__ nW,
    const float* __restrict__ nb, float* __restrict__ x)
{
    int out_idx = blockIdx.x * 4 + (threadIdx.x >> 6);
    int lane = threadIdx.x & 63;
    const float4* src = (const float4*)(in + (size_t)out_idx * E);
    float4 a = src[lane];
    float4 wv = ((const float4*)nW)[lane];
    float s = a.x * wv.x + a.y * wv.y + a.z * wv.z + a.w * wv.w;
    s = waveReduceSum(s);
    if (lane == 0) x[out_idx] = s + nb[0];
}

// ---------------------------------------------------------------------------
__global__ __launch_bounds__(64) void z2_kernel(
    const float* __restrict__ x, const float* __restrict__ A2,
    const float* __restrict__ b2, float* __restrict__ z2)
{
    int b = blockIdx.x >> 7;
    int i = blockIdx.x & 127;
    int s = threadIdx.x;
    __shared__ float xs[T];
    xs[s] = x[((size_t)b * T + s) * IDIM + i];
    __syncthreads();
    float acc = b2[s];
    const float* arow = A2 + s * T;
#pragma unroll 8
    for (int tt = 0; tt < T; ++tt) acc += xs[tt] * arow[tt];
    z2[((size_t)b * IDIM + i) * T + s] = acc;
}

// ---------------------------------------------------------------------------
// Flag-array split barrier (per-quarter, 64 blocks). No atomics:
// arrive = one relaxed flag store (flag[bid], 64 B apart, monotonic phase);
// wait   = wave 7's 64 lanes poll all 64 flags in ONE coalesced round-trip.
// Payload visibility: each wave drains vmcnt at the arrive's __syncthreads,
// so the block's global stores complete before the flag store is issued.
// Flags indexed by bid: with q = bid&3, a quarter's 64 flags are the bids
// {q, q+4, q+8, ...} — strided but one vector round-trip either way.
#define FLG_STRIDE 16   // 64 B between flags: no same-cacheline store serial.
__device__ __forceinline__ void qarrive(int* cnt, int bid, int ph) {
    __syncthreads();                     // all waves drain vmem before arrive
    if (threadIdx.x == NT - 1) {
        asm volatile("s_waitcnt vmcnt(0) lgkmcnt(0)" ::: "memory");
        astore_i(cnt + bid * FLG_STRIDE, ph);
    }
}
__device__ __forceinline__ void qwait(int* cnt, int q, int ph) {
    if (threadIdx.x >= NT - 64) {
        int lane = threadIdx.x & 63;
        const int* fp = cnt + (lane * 4 + q) * FLG_STRIDE;  // bids with bid&3==q
        int spins = 0;
        while (!__all(aload_i(fp) >= ph)) {
            if (++spins > (1 << 16)) break;  // fail visibly, never hang
        }
    }
    __syncthreads();
}

// ---------------------------------------------------------------------------
// Persistent scan — R16 chassis (512 thr, flag-array split barriers, de-dup
// attn) with XCD-PAIR-LOCAL quarters: q = bid&3, ns = bid>>2. Under
// round-robin block->XCD dispatch, quarter q's 64 blocks land on XCD pair
// {q, q+4}, making all barrier flags and h/c/wbuf exchanges 2-XCD-local
// (R7 had this mapping but bundled with spilling preloads — never isolated).
// VGPR-cliff rule (R9/R10/R11): no live ranges extended across phases.
__global__ __launch_bounds__(NT, 1) void scan_kernel(
    const float* __restrict__ x, const float* __restrict__ z2,
    const float* __restrict__ A1, const float* __restrict__ b1,
    const float* __restrict__ a3w,
    const float* __restrict__ Wih, const float* __restrict__ Whh,
    const float* __restrict__ bih, const float* __restrict__ bhh,
    float* __restrict__ wbuf, float* __restrict__ hbuf, float* __restrict__ cbuf,
    int* __restrict__ cnt, float* __restrict__ out)
{
    __shared__ float pool[POOL_F];
    float* Wlds = pool + OFF_W;
    float* At4  = pool + OFF_A;
    float* hcs  = pool + OFF_HC;
    float* z1s  = pool + OFF_Z1;
    float* redl = pool + OFF_RED;
    float* blds = pool + OFF_BI;

    const int tid  = threadIdx.x;
    const int bid  = blockIdx.x;
    const int lane = tid & 63, wave = tid >> 6;
    const int q = bid & 3, ns = bid >> 2;      // XCD-pair-local quarters
    const int b0 = q * 32, n0 = ns * 8;
    const int ab = b0 + (ns >> 1);             // attn batch
    const bool is_attn = ((ns & 1) == 0);      // one attn block per batch
    const int jg = lane & 7, bg = lane >> 3;   // compute tile coords
    const int half = tid >> 8;                 // h-staging: 2 halves x 2 chunks
    const int sbh = (tid & 255) >> 3;          // batch row 0..31
    const int st8 = tid & 7;

    // one-time: weight slice (cols j = g*512 + n0 + nn; 4 gates x 8 n)
    for (int idx = tid; idx < 640 * 32; idx += NT) {
        int jj = idx / 640, k = idx - jj * 640;
        int j = (jj >> 3) * 512 + n0 + (jj & 7);
        Wlds[k * 32 + jj] = (k < 128) ? Wih[(size_t)j * 128 + k]
                                      : Whh[(size_t)j * 512 + (k - 128)];
    }
    if (tid < 32) {
        int j = (tid >> 3) * 512 + n0 + (tid & 7);
        blds[tid] = bih[j] + bhh[j];
    }

    // block-local cell state: thread tid<256 owns c[b0 + (tid>>3)][n0 + (tid&7)]
    float cown = 0.f;

    int ph = 0;
    for (int t = 0; t < T; ++t) {
        // -------- issue coherent h-tile prefetch (latency hides under attn)
        float4 hv[8];
        {
            const float* hrow = hbuf + (size_t)(b0 + sbh) * H + half * 256;
#pragma unroll
            for (int cc = 0; cc < 2; ++cc)
#pragma unroll
                for (int qq = 0; qq < 4; ++qq)
                    hv[cc * 4 + qq] = cload4(hrow + cc * 128 + (st8 + 8 * qq) * 4);
        }

        // -------- phase A: attention (EVEN-ns blocks only; full batch) ------
        if (is_attn) {
            hcs[tid]     = aload(hbuf + (size_t)ab * H + tid);
            hcs[H + tid] = aload(cbuf + (size_t)ab * H + tid);
            __syncthreads();
            // z1: scalar stride-64 LDS reads (2-way, conflict-free)
            for (int r = 0; r < 8; ++r) {
                int tt = r * 8 + wave;
                const float* row = A1 + (size_t)tt * (2 * H);
                float p = 0.f;
#pragma unroll
                for (int qq = 0; qq < 16; ++qq)
                    p += row[lane + qq * 64] * hcs[lane + qq * 64];
                p = waveReduceSum(p);
                if (lane == 0) z1s[tt] = p + b1[tt];
            }
            __syncthreads();
            // z3: 4 threads per driver row, 16 t each (R4-verified indexing)
            int i = tid >> 2, qt = tid & 3;
            const float* z2r = z2 + ((size_t)ab * IDIM + i) * T + qt * 16;
            const float* z1p = z1s + qt * 16;
            const float* a3p = a3w + qt * 16;
            float accz = 0.f;
#pragma unroll
            for (int qq = 0; qq < 4; ++qq) {
                float4 zv  = *(const float4*)(z2r + qq * 4);
                float4 z1v = *(const float4*)(z1p + qq * 4);
                float4 a3v = *(const float4*)(a3p + qq * 4);
                accz += fast_tanh(z1v.x + zv.x) * a3v.x
                      + fast_tanh(z1v.y + zv.y) * a3v.y
                      + fast_tanh(z1v.z + zv.z) * a3v.z
                      + fast_tanh(z1v.w + zv.w) * a3v.w;
            }
            accz += __shfl_xor(accz, 1, 64);
            accz += __shfl_xor(accz, 2, 64);
            if (qt == 0) redl[i] = accz;
            __syncthreads();
            if (wave == 0) {
                float v0 = redl[lane], v1 = redl[lane + 64];
                float m = fmaxf(v0, v1);
                for (int off = 32; off > 0; off >>= 1)
                    m = fmaxf(m, __shfl_xor(m, off, 64));
                float e0 = __expf(v0 - m), e1 = __expf(v1 - m);
                float inv = 1.0f / waveReduceSum(e0 + e1);
                const float* xt = x + ((size_t)ab * T + t) * IDIM;
                astore(wbuf + ab * IDIM + lane,      e0 * inv * xt[lane]);
                astore(wbuf + ab * IDIM + lane + 64, e1 * inv * xt[lane + 64]);
            }
        }

        // -------- ARRIVE #1 (wbuf published); flags settle under B1 ---------
        ++ph;
        qarrive(cnt, bid, ph);

        // -------- stage h-tile into LDS (transposed, stride-34) -------------
        waitvm0();
        {
#pragma unroll
            for (int cc = 0; cc < 2; ++cc)
#pragma unroll
                for (int qq = 0; qq < 4; ++qq) {
                    float4 v = hv[cc * 4 + qq];
                    float* d = At4 + (half * 2 + cc) * AT_CH
                             + ((st8 + 8 * qq) * 4) * AT_STRIDE + sbh;
                    d[0] = v.x; d[AT_STRIDE] = v.y;
                    d[2 * AT_STRIDE] = v.z; d[3 * AT_STRIDE] = v.w;
                }
        }
        __syncthreads();

        // -------- B1: h-part GEMM, wave k-split (64 kk each of 512) ---------
        float acc[4][4];   // [ji (j within group)][eb (b within group)]
#pragma unroll
        for (int a_ = 0; a_ < 4; ++a_)
#pragma unroll
            for (int b_ = 0; b_ < 4; ++b_) acc[a_][b_] = 0.f;
        {
            const float* Ab = At4 + (wave >> 1) * AT_CH
                            + ((wave & 1) * 64) * AT_STRIDE + bg * 4;
            const float* Wb = Wlds + (size_t)(128 + wave * 64) * 32 + jg * 4;
#pragma unroll 8
            for (int i = 0; i < 64; ++i) {
                float4 wv = *(const float4*)(Wb + i * 32);
                float2 a01 = *(const float2*)(Ab + i * AT_STRIDE);
                float2 a23 = *(const float2*)(Ab + i * AT_STRIDE + 2);
                float av[4] = {a01.x, a01.y, a23.x, a23.y};
                const float wj[4] = {wv.x, wv.y, wv.z, wv.w};
#pragma unroll
                for (int a_ = 0; a_ < 4; ++a_)
#pragma unroll
                    for (int b_ = 0; b_ < 4; ++b_)
                        acc[a_][b_] += wj[a_] * av[b_];
            }
        }

        qwait(cnt, q, ph);                    // wbuf ready (quarter-local)

        // -------- stage w-tile, B2: w-part GEMM (16 kk each of 128) ---------
        {
            const float* wrow = wbuf + (size_t)(b0 + (tid >> 4)) * IDIM;
            float4 w0 = cload4(wrow + (tid & 15) * 4);
            float4 w1 = cload4(wrow + ((tid & 15) + 16) * 4);
            waitvm0();
            int sbw = tid >> 4, st16 = tid & 15;
            float* d0 = At4 + (st16 * 4) * AT_STRIDE + sbw;
            d0[0] = w0.x; d0[AT_STRIDE] = w0.y;
            d0[2 * AT_STRIDE] = w0.z; d0[3 * AT_STRIDE] = w0.w;
            float* d1 = At4 + ((st16 + 16) * 4) * AT_STRIDE + sbw;
            d1[0] = w1.x; d1[AT_STRIDE] = w1.y;
            d1[2 * AT_STRIDE] = w1.z; d1[3 * AT_STRIDE] = w1.w;
        }
        __syncthreads();
        {
            const float* Ab = At4 + (wave * 16) * AT_STRIDE + bg * 4;
            const float* Wb = Wlds + (size_t)(wave * 16) * 32 + jg * 4;
#pragma unroll
            for (int i = 0; i < 16; ++i) {
                float4 wv = *(const float4*)(Wb + i * 32);
                float2 a01 = *(const float2*)(Ab + i * AT_STRIDE);
                float2 a23 = *(const float2*)(Ab + i * AT_STRIDE + 2);
                float av[4] = {a01.x, a01.y, a23.x, a23.y};
                const float wj[4] = {wv.x, wv.y, wv.z, wv.w};
#pragma unroll
                for (int a_ = 0; a_ < 4; ++a_)
#pragma unroll
                    for (int b_ = 0; b_ < 4; ++b_)
                        acc[a_][b_] += wj[a_] * av[b_];
            }
        }

        // -------- 8-way cross-wave k-reduce (stride-33 + jg-rotation) -------
        float* red4 = At4 + AT_CH;            // 8448 floats, chunks 1-2 (dead)
#pragma unroll
        for (int ji = 0; ji < 4; ++ji) {
            int r = jg * 4 + ji;
#pragma unroll
            for (int eb = 0; eb < 4; ++eb)
                red4[wave * 1056 + r * 33 + bg * 4 + ((eb + jg) & 3)] = acc[ji][eb];
        }
        __syncthreads();

        float* glds = At4;                    // chunk 0 (dead after B2)
        if (tid < 256) {
            int jj = tid >> 3, b8 = tid & 7;
            int rot = jj >> 2;
            float bias = blds[jj];
            float s[4] = {bias, bias, bias, bias};
#pragma unroll
            for (int w = 0; w < 8; ++w) {
                const float* rp = red4 + w * 1056 + jj * 33 + b8 * 4;
#pragma unroll
                for (int eb = 0; eb < 4; ++eb)
                    s[eb] += rp[(eb + rot) & 3];
            }
#pragma unroll
            for (int eb = 0; eb < 4; ++eb)
                glds[jj * 33 + b8 * 4 + eb] = s[eb];
        }
        __syncthreads();
        float hnew = 0.f;
        if (tid < 256) {
            int ub = tid >> 3, un = tid & 7;
            float ig = glds[(0 * 8 + un) * 33 + ub];
            float fg = glds[(1 * 8 + un) * 33 + ub];
            float gg = glds[(2 * 8 + un) * 33 + ub];
            float og = glds[(3 * 8 + un) * 33 + ub];
            int gb = b0 + ub, gn = n0 + un;
            float cnew = sigmoidf_(fg) * cown + sigmoidf_(ig) * tanhf(gg);
            hnew = sigmoidf_(og) * tanhf(cnew);
            cown = cnew;
            astore(cbuf + (size_t)gb * H + gn, cnew);
            astore(hbuf + (size_t)gb * H + gn, hnew);
        }

        // -------- ARRIVE #2 (h,c published); out-store under settle ---------
        ++ph;
        qarrive(cnt, bid, ph);
        if (tid < 256) {
            int gb = b0 + (tid >> 3), gn = n0 + (tid & 7);
            out[((size_t)gb * T + t) * H + gn] = hnew;
        }
        qwait(cnt, q, ph);                    // h_{t+1}, c_{t+1} ready
    }
}

// ---------------------------------------------------------------------------
extern "C" void kernel_launch(void* const* d_in, const int* in_sizes, int n_in,
                              void* d_out, int out_size, void* d_ws, size_t ws_size,
                              hipStream_t stream)
{
    const float* input  = (const float*)d_in[0];
    const float* news_W = (const float*)d_in[1];
    const float* news_b = (const float*)d_in[2];
    const float* A1     = (const float*)d_in[3];
    const float* b1     = (const float*)d_in[4];
    const float* A2     = (const float*)d_in[5];
    const float* b2     = (const float*)d_in[6];
    const float* a3w    = (const float*)d_in[7];
    // d_in[8] = attn3_b: softmax-invariant, unused
    const float* Wih    = (const float*)d_in[9];
    const float* Whh    = (const float*)d_in[10];
    const float* bih    = (const float*)d_in[11];
    const float* bhh    = (const float*)d_in[12];
    float* out = (float*)d_out;

    char* ws = (char*)d_ws;
    size_t off = 0;
    auto alloc = [&](size_t nelem) {
        float* p = (float*)(ws + off);
        off += ((nelem * 4 + 255) / 256) * 256;
        return p;
    };
    float* x    = alloc((size_t)B * T * IDIM);   // 4 MB
    float* z2   = alloc((size_t)B * IDIM * T);   // 4 MB
    float* wbuf = alloc((size_t)B * IDIM);       // 64 KB
    float* hbuf = alloc((size_t)B * H);          // single h buffer
    float* cbuf = alloc((size_t)B * H);          // single c buffer
    int*   cnt  = (int*)alloc(4096);             // 256 flags x 16-int stride

    hipMemsetAsync(hbuf, 0, (size_t)B * H * 4, stream);
    hipMemsetAsync(cbuf, 0, (size_t)B * H * 4, stream);
    hipMemsetAsync(cnt, 0, 4096 * 4, stream);

    news_kernel<<<B * T * IDIM / 4, 256, 0, stream>>>(input, news_W, news_b, x);
    z2_kernel<<<B * IDIM, 64, 0, stream>>>(x, A2, b2, z2);
    scan_kernel<<<256, NT, 0, stream>>>(x, z2, A1, b1, a3w, Wih, Whh, bih, bhh,
                                        wbuf, hbuf, cbuf, cnt, out);
}

// Round 18
// 1137.329 us; speedup vs baseline: 1.2656x; 1.0213x over previous
//
#include <hip/hip_runtime.h>
#include <cstdint>
#include <cstddef>

#define B 128
#define T 64
#define IDIM 128
#define E 256
#define H 512
#define NT 512

#define AT_STRIDE 34
#define AT_CH (128 * AT_STRIDE)   // 4352 floats per 128-k chunk

// LDS pool offsets (floats)
#define OFF_W   0                       // Wlds[640][32] = 20480
#define OFF_A   20480                   // At4[4][AT_CH] = 17408
#define OFF_HC  (OFF_A + 4 * AT_CH)     // hc[1024]
#define OFF_Z1  (OFF_HC + 1024)        // z1s[64]
#define OFF_RED (OFF_Z1 + 64)          // red[128]
#define OFF_BI  (OFF_RED + 128)        // bias[32]
#define POOL_F  (OFF_BI + 32)          // 39136 floats = 156544 B (<160K)

__device__ __forceinline__ float waveReduceSum(float v) {
    for (int off = 32; off > 0; off >>= 1) v += __shfl_xor(v, off, 64);
    return v;
}

__device__ __forceinline__ float fast_tanh(float v) {
    float a = fabsf(v);
    float e = __expf(-2.f * a);
    float r = (1.f - e) * __builtin_amdgcn_rcpf(1.f + e);
    return copysignf(r, v);
}

__device__ __forceinline__ float sigmoidf_(float x) {
    return 1.0f / (1.0f + __expf(-x));
}

// Coherent scalar accessors (bypass stale L1/L2; served at coherence point).
__device__ __forceinline__ float aload(const float* p) {
    return __hip_atomic_load(p, __ATOMIC_RELAXED, __HIP_MEMORY_SCOPE_AGENT);
}
__device__ __forceinline__ void astore(float* p, float v) {
    __hip_atomic_store(p, v, __ATOMIC_RELAXED, __HIP_MEMORY_SCOPE_AGENT);
}
__device__ __forceinline__ int aload_i(const int* p) {
    return __hip_atomic_load(p, __ATOMIC_RELAXED, __HIP_MEMORY_SCOPE_AGENT);
}
__device__ __forceinline__ void astore_i(int* p, int v) {
    __hip_atomic_store(p, v, __ATOMIC_RELAXED, __HIP_MEMORY_SCOPE_AGENT);
}

// Coherent 16B load (async — must waitvm0() before using the result).
__device__ __forceinline__ float4 cload4(const float* p) {
    float4 v;
    asm volatile("global_load_dwordx4 %0, %1, off sc0 sc1" : "=v"(v) : "v"(p));
    return v;
}
__device__ __forceinline__ void waitvm0() {
    asm volatile("s_waitcnt vmcnt(0)" ::: "memory");
}

// ---------------------------------------------------------------------------
__global__ __launch_bounds__(256) void news_kernel(
    const float* __restrict__ in, const float* __restrict__ nW,
    const float* __restrict__ nb, float* __restrict__ x)
{
    int out_idx = blockIdx.x * 4 + (threadIdx.x >> 6);
    int lane = threadIdx.x & 63;
    const float4* src = (const float4*)(in + (size_t)out_idx * E);
    float4 a = src[lane];
    float4 wv = ((const float4*)nW)[lane];
    float s = a.x * wv.x + a.y * wv.y + a.z * wv.z + a.w * wv.w;
    s = waveReduceSum(s);
    if (lane == 0) x[out_idx] = s + nb[0];
}

// ---------------------------------------------------------------------------
__global__ __launch_bounds__(64) void z2_kernel(
    const float* __restrict__ x, const float* __restrict__ A2,
    const float* __restrict__ b2, float* __restrict__ z2)
{
    int b = blockIdx.x >> 7;
    int i = blockIdx.x & 127;
    int s = threadIdx.x;
    __shared__ float xs[T];
    xs[s] = x[((size_t)b * T + s) * IDIM + i];
    __syncthreads();
    float acc = b2[s];
    const float* arow = A2 + s * T;
#pragma unroll 8
    for (int tt = 0; tt < T; ++tt) acc += xs[tt] * arow[tt];
    z2[((size_t)b * IDIM + i) * T + s] = acc;
}

// ---------------------------------------------------------------------------
// Flag-array split barrier (per-quarter, 64 blocks). No atomics.
// Flags indexed by (q, ns): flag[q*64+ns] at 16 B stride — a quarter's 64
// flags occupy 16 cache lines (vs 64 with the old 64 B layout), so the hot
// qwait vector-poll touches 4x fewer IF$ sectors per iteration. Store side
// (4 stores/line) settles inside the arrive->wait window, off the critical
// path. Payload visibility: each wave drains vmcnt at the arrive's
// __syncthreads, so the block's global stores complete before the flag store.
#define FLG_STRIDE 4    // 16 B between flags.
__device__ __forceinline__ void qarrive(int* cnt, int q, int ns, int ph) {
    __syncthreads();                     // all waves drain vmem before arrive
    if (threadIdx.x == NT - 1) {
        asm volatile("s_waitcnt vmcnt(0) lgkmcnt(0)" ::: "memory");
        astore_i(cnt + (q * 64 + ns) * FLG_STRIDE, ph);
    }
}
__device__ __forceinline__ void qwait(int* cnt, int q, int ph) {
    if (threadIdx.x >= NT - 64) {
        int lane = threadIdx.x & 63;
        const int* fp = cnt + (q * 64 + lane) * FLG_STRIDE;
        int spins = 0;
        while (!__all(aload_i(fp) >= ph)) {
            if (++spins > (1 << 16)) break;  // fail visibly, never hang
        }
    }
    __syncthreads();
}

// ---------------------------------------------------------------------------
// Persistent scan — R17 chassis (512 thr, flag-array split barriers, de-dup
// attn, XCD-pair-local quarters q = bid&3) with two latency cuts:
// (1) z1 2-row ILP: paired rows share the LDS operand read and run two
//     independent L2 streams per wave (halves exposed L2 latency in the
//     longest serial phase; short-lived registers only — cliff-safe);
// (2) colocated barrier flags (see above).
// VGPR-cliff rule (R9/R10/R11): no live ranges extended across phases.
__global__ __launch_bounds__(NT, 1) void scan_kernel(
    const float* __restrict__ x, const float* __restrict__ z2,
    const float* __restrict__ A1, const float* __restrict__ b1,
    const float* __restrict__ a3w,
    const float* __restrict__ Wih, const float* __restrict__ Whh,
    const float* __restrict__ bih, const float* __restrict__ bhh,
    float* __restrict__ wbuf, float* __restrict__ hbuf, float* __restrict__ cbuf,
    int* __restrict__ cnt, float* __restrict__ out)
{
    __shared__ float pool[POOL_F];
    float* Wlds = pool + OFF_W;
    float* At4  = pool + OFF_A;
    float* hcs  = pool + OFF_HC;
    float* z1s  = pool + OFF_Z1;
    float* redl = pool + OFF_RED;
    float* blds = pool + OFF_BI;

    const int tid  = threadIdx.x;
    const int bid  = blockIdx.x;
    const int lane = tid & 63, wave = tid >> 6;
    const int q = bid & 3, ns = bid >> 2;      // XCD-pair-local quarters
    const int b0 = q * 32, n0 = ns * 8;
    const int ab = b0 + (ns >> 1);             // attn batch
    const bool is_attn = ((ns & 1) == 0);      // one attn block per batch
    const int jg = lane & 7, bg = lane >> 3;   // compute tile coords
    const int half = tid >> 8;                 // h-staging: 2 halves x 2 chunks
    const int sbh = (tid & 255) >> 3;          // batch row 0..31
    const int st8 = tid & 7;

    // one-time: weight slice (cols j = g*512 + n0 + nn; 4 gates x 8 n)
    for (int idx = tid; idx < 640 * 32; idx += NT) {
        int jj = idx / 640, k = idx - jj * 640;
        int j = (jj >> 3) * 512 + n0 + (jj & 7);
        Wlds[k * 32 + jj] = (k < 128) ? Wih[(size_t)j * 128 + k]
                                      : Whh[(size_t)j * 512 + (k - 128)];
    }
    if (tid < 32) {
        int j = (tid >> 3) * 512 + n0 + (tid & 7);
        blds[tid] = bih[j] + bhh[j];
    }

    // block-local cell state: thread tid<256 owns c[b0 + (tid>>3)][n0 + (tid&7)]
    float cown = 0.f;

    int ph = 0;
    for (int t = 0; t < T; ++t) {
        // -------- issue coherent h-tile prefetch (latency hides under attn)
        float4 hv[8];
        {
            const float* hrow = hbuf + (size_t)(b0 + sbh) * H + half * 256;
#pragma unroll
            for (int cc = 0; cc < 2; ++cc)
#pragma unroll
                for (int qq = 0; qq < 4; ++qq)
                    hv[cc * 4 + qq] = cload4(hrow + cc * 128 + (st8 + 8 * qq) * 4);
        }

        // -------- phase A: attention (EVEN-ns blocks only; full batch) ------
        if (is_attn) {
            hcs[tid]     = aload(hbuf + (size_t)ab * H + tid);
            hcs[H + tid] = aload(cbuf + (size_t)ab * H + tid);
            __syncthreads();
            // z1: 2-row ILP — paired rows share the LDS operand read and
            // stream two independent A1 rows from L2 concurrently.
            for (int r = 0; r < 4; ++r) {
                int t0 = r * 16 + wave;
                int t1 = t0 + 8;
                const float* r0 = A1 + (size_t)t0 * (2 * H);
                const float* r1 = A1 + (size_t)t1 * (2 * H);
                float p0 = 0.f, p1 = 0.f;
#pragma unroll
                for (int qq = 0; qq < 16; ++qq) {
                    float hcv = hcs[lane + qq * 64];
                    p0 += r0[lane + qq * 64] * hcv;
                    p1 += r1[lane + qq * 64] * hcv;
                }
                p0 = waveReduceSum(p0);
                p1 = waveReduceSum(p1);
                if (lane == 0) {
                    z1s[t0] = p0 + b1[t0];
                    z1s[t1] = p1 + b1[t1];
                }
            }
            __syncthreads();
            // z3: 4 threads per driver row, 16 t each (R4-verified indexing)
            int i = tid >> 2, qt = tid & 3;
            const float* z2r = z2 + ((size_t)ab * IDIM + i) * T + qt * 16;
            const float* z1p = z1s + qt * 16;
            const float* a3p = a3w + qt * 16;
            float accz = 0.f;
#pragma unroll
            for (int qq = 0; qq < 4; ++qq) {
                float4 zv  = *(const float4*)(z2r + qq * 4);
                float4 z1v = *(const float4*)(z1p + qq * 4);
                float4 a3v = *(const float4*)(a3p + qq * 4);
                accz += fast_tanh(z1v.x + zv.x) * a3v.x
                      + fast_tanh(z1v.y + zv.y) * a3v.y
                      + fast_tanh(z1v.z + zv.z) * a3v.z
                      + fast_tanh(z1v.w + zv.w) * a3v.w;
            }
            accz += __shfl_xor(accz, 1, 64);
            accz += __shfl_xor(accz, 2, 64);
            if (qt == 0) redl[i] = accz;
            __syncthreads();
            if (wave == 0) {
                float v0 = redl[lane], v1 = redl[lane + 64];
                float m = fmaxf(v0, v1);
                for (int off = 32; off > 0; off >>= 1)
                    m = fmaxf(m, __shfl_xor(m, off, 64));
                float e0 = __expf(v0 - m), e1 = __expf(v1 - m);
                float inv = 1.0f / waveReduceSum(e0 + e1);
                const float* xt = x + ((size_t)ab * T + t) * IDIM;
                astore(wbuf + ab * IDIM + lane,      e0 * inv * xt[lane]);
                astore(wbuf + ab * IDIM + lane + 64, e1 * inv * xt[lane + 64]);
            }
        }

        // -------- ARRIVE #1 (wbuf published); flags settle under B1 ---------
        ++ph;
        qarrive(cnt, q, ns, ph);

        // -------- stage h-tile into LDS (transposed, stride-34) -------------
        waitvm0();
        {
#pragma unroll
            for (int cc = 0; cc < 2; ++cc)
#pragma unroll
                for (int qq = 0; qq < 4; ++qq) {
                    float4 v = hv[cc * 4 + qq];
                    float* d = At4 + (half * 2 + cc) * AT_CH
                             + ((st8 + 8 * qq) * 4) * AT_STRIDE + sbh;
                    d[0] = v.x; d[AT_STRIDE] = v.y;
                    d[2 * AT_STRIDE] = v.z; d[3 * AT_STRIDE] = v.w;
                }
        }
        __syncthreads();

        // -------- B1: h-part GEMM, wave k-split (64 kk each of 512) ---------
        float acc[4][4];   // [ji (j within group)][eb (b within group)]
#pragma unroll
        for (int a_ = 0; a_ < 4; ++a_)
#pragma unroll
            for (int b_ = 0; b_ < 4; ++b_) acc[a_][b_] = 0.f;
        {
            const float* Ab = At4 + (wave >> 1) * AT_CH
                            + ((wave & 1) * 64) * AT_STRIDE + bg * 4;
            const float* Wb = Wlds + (size_t)(128 + wave * 64) * 32 + jg * 4;
#pragma unroll 8
            for (int i = 0; i < 64; ++i) {
                float4 wv = *(const float4*)(Wb + i * 32);
                float2 a01 = *(const float2*)(Ab + i * AT_STRIDE);
                float2 a23 = *(const float2*)(Ab + i * AT_STRIDE + 2);
                float av[4] = {a01.x, a01.y, a23.x, a23.y};
                const float wj[4] = {wv.x, wv.y, wv.z, wv.w};
#pragma unroll
                for (int a_ = 0; a_ < 4; ++a_)
#pragma unroll
                    for (int b_ = 0; b_ < 4; ++b_)
                        acc[a_][b_] += wj[a_] * av[b_];
            }
        }

        qwait(cnt, q, ph);                    // wbuf ready (quarter-local)

        // -------- stage w-tile, B2: w-part GEMM (16 kk each of 128) ---------
        {
            const float* wrow = wbuf + (size_t)(b0 + (tid >> 4)) * IDIM;
            float4 w0 = cload4(wrow + (tid & 15) * 4);
            float4 w1 = cload4(wrow + ((tid & 15) + 16) * 4);
            waitvm0();
            int sbw = tid >> 4, st16 = tid & 15;
            float* d0 = At4 + (st16 * 4) * AT_STRIDE + sbw;
            d0[0] = w0.x; d0[AT_STRIDE] = w0.y;
            d0[2 * AT_STRIDE] = w0.z; d0[3 * AT_STRIDE] = w0.w;
            float* d1 = At4 + ((st16 + 16) * 4) * AT_STRIDE + sbw;
            d1[0] = w1.x; d1[AT_STRIDE] = w1.y;
            d1[2 * AT_STRIDE] = w1.z; d1[3 * AT_STRIDE] = w1.w;
        }
        __syncthreads();
        {
            const float* Ab = At4 + (wave * 16) * AT_STRIDE + bg * 4;
            const float* Wb = Wlds + (size_t)(wave * 16) * 32 + jg * 4;
#pragma unroll
            for (int i = 0; i < 16; ++i) {
                float4 wv = *(const float4*)(Wb + i * 32);
                float2 a01 = *(const float2*)(Ab + i * AT_STRIDE);
                float2 a23 = *(const float2*)(Ab + i * AT_STRIDE + 2);
                float av[4] = {a01.x, a01.y, a23.x, a23.y};
                const float wj[4] = {wv.x, wv.y, wv.z, wv.w};
#pragma unroll
                for (int a_ = 0; a_ < 4; ++a_)
#pragma unroll
                    for (int b_ = 0; b_ < 4; ++b_)
                        acc[a_][b_] += wj[a_] * av[b_];
            }
        }

        // -------- 8-way cross-wave k-reduce (stride-33 + jg-rotation) -------
        float* red4 = At4 + AT_CH;            // 8448 floats, chunks 1-2 (dead)
#pragma unroll
        for (int ji = 0; ji < 4; ++ji) {
            int r = jg * 4 + ji;
#pragma unroll
            for (int eb = 0; eb < 4; ++eb)
                red4[wave * 1056 + r * 33 + bg * 4 + ((eb + jg) & 3)] = acc[ji][eb];
        }
        __syncthreads();

        float* glds = At4;                    // chunk 0 (dead after B2)
        if (tid < 256) {
            int jj = tid >> 3, b8 = tid & 7;
            int rot = jj >> 2;
            float bias = blds[jj];
            float s[4] = {bias, bias, bias, bias};
#pragma unroll
            for (int w = 0; w < 8; ++w) {
                const float* rp = red4 + w * 1056 + jj * 33 + b8 * 4;
#pragma unroll
                for (int eb = 0; eb < 4; ++eb)
                    s[eb] += rp[(eb + rot) & 3];
            }
#pragma unroll
            for (int eb = 0; eb < 4; ++eb)
                glds[jj * 33 + b8 * 4 + eb] = s[eb];
        }
        __syncthreads();
        float hnew = 0.f;
        if (tid < 256) {
            int ub = tid >> 3, un = tid & 7;
            float ig = glds[(0 * 8 + un) * 33 + ub];
            float fg = glds[(1 * 8 + un) * 33 + ub];
            float gg = glds[(2 * 8 + un) * 33 + ub];
            float og = glds[(3 * 8 + un) * 33 + ub];
            int gb = b0 + ub, gn = n0 + un;
            float cnew = sigmoidf_(fg) * cown + sigmoidf_(ig) * tanhf(gg);
            hnew = sigmoidf_(og) * tanhf(cnew);
            cown = cnew;
            astore(cbuf + (size_t)gb * H + gn, cnew);
            astore(hbuf + (size_t)gb * H + gn, hnew);
        }

        // -------- ARRIVE #2 (h,c published); out-store under settle ---------
        ++ph;
        qarrive(cnt, q, ns, ph);
        if (tid < 256) {
            int gb = b0 + (tid >> 3), gn = n0 + (tid & 7);
            out[((size_t)gb * T + t) * H + gn] = hnew;
        }
        qwait(cnt, q, ph);                    // h_{t+1}, c_{t+1} ready
    }
}

// ---------------------------------------------------------------------------
extern "C" void kernel_launch(void* const* d_in, const int* in_sizes, int n_in,
                              void* d_out, int out_size, void* d_ws, size_t ws_size,
                              hipStream_t stream)
{
    const float* input  = (const float*)d_in[0];
    const float* news_W = (const float*)d_in[1];
    const float* news_b = (const float*)d_in[2];
    const float* A1     = (const float*)d_in[3];
    const float* b1     = (const float*)d_in[4];
    const float* A2     = (const float*)d_in[5];
    const float* b2     = (const float*)d_in[6];
    const float* a3w    = (const float*)d_in[7];
    // d_in[8] = attn3_b: softmax-invariant, unused
    const float* Wih    = (const float*)d_in[9];
    const float* Whh    = (const float*)d_in[10];
    const float* bih    = (const float*)d_in[11];
    const float* bhh    = (const float*)d_in[12];
    float* out = (float*)d_out;

    char* ws = (char*)d_ws;
    size_t off = 0;
    auto alloc = [&](size_t nelem) {
        float* p = (float*)(ws + off);
        off += ((nelem * 4 + 255) / 256) * 256;
        return p;
    };
    float* x    = alloc((size_t)B * T * IDIM);   // 4 MB
    float* z2   = alloc((size_t)B * IDIM * T);   // 4 MB
    float* wbuf = alloc((size_t)B * IDIM);       // 64 KB
    float* hbuf = alloc((size_t)B * H);          // single h buffer
    float* cbuf = alloc((size_t)B * H);          // single c buffer
    int*   cnt  = (int*)alloc(2048);             // 256 flags x 4-int stride

    hipMemsetAsync(hbuf, 0, (size_t)B * H * 4, stream);
    hipMemsetAsync(cbuf, 0, (size_t)B * H * 4, stream);
    hipMemsetAsync(cnt, 0, 2048 * 4, stream);

    news_kernel<<<B * T * IDIM / 4, 256, 0, stream>>>(input, news_W, news_b, x);
    z2_kernel<<<B * IDIM, 64, 0, stream>>>(x, A2, b2, z2);
    scan_kernel<<<256, NT, 0, stream>>>(x, z2, A1, b1, a3w, Wih, Whh, bih, bhh,
                                        wbuf, hbuf, cbuf, cnt, out);
}

// Round 19
// 1087.175 us; speedup vs baseline: 1.3240x; 1.0461x over previous
//
#include <hip/hip_runtime.h>
#include <cstdint>
#include <cstddef>

#define B 128
#define T 64
#define IDIM 128
#define E 256
#define H 512
#define NT 512

#define AT_STRIDE 34
#define AT_CH (128 * AT_STRIDE)   // 4352 floats per 128-k chunk

// LDS pool offsets (floats)
#define OFF_W   0                       // Wlds[640][32] = 20480
#define OFF_A   20480                   // At4[4][AT_CH] = 17408
#define OFF_HC  (OFF_A + 4 * AT_CH)     // hc[1024]
#define OFF_Z1  (OFF_HC + 1024)        // z1s[64]
#define OFF_RED (OFF_Z1 + 64)          // red[128]
#define OFF_BI  (OFF_RED + 128)        // bias[32]
#define OFF_B1L (OFF_BI + 32)          // b1 staged [64]
#define POOL_F  (OFF_B1L + 64)         // 39200 floats = 156800 B (<160K)

__device__ __forceinline__ float waveReduceSum(float v) {
    for (int off = 32; off > 0; off >>= 1) v += __shfl_xor(v, off, 64);
    return v;
}

__device__ __forceinline__ float fast_tanh(float v) {
    float a = fabsf(v);
    float e = __expf(-2.f * a);
    float r = (1.f - e) * __builtin_amdgcn_rcpf(1.f + e);
    return copysignf(r, v);
}

__device__ __forceinline__ float sigmoidf_(float x) {
    return 1.0f / (1.0f + __expf(-x));
}

// Coherent scalar accessors (bypass stale L1/L2; served at coherence point).
__device__ __forceinline__ float aload(const float* p) {
    return __hip_atomic_load(p, __ATOMIC_RELAXED, __HIP_MEMORY_SCOPE_AGENT);
}
__device__ __forceinline__ void astore(float* p, float v) {
    __hip_atomic_store(p, v, __ATOMIC_RELAXED, __HIP_MEMORY_SCOPE_AGENT);
}
__device__ __forceinline__ int aload_i(const int* p) {
    return __hip_atomic_load(p, __ATOMIC_RELAXED, __HIP_MEMORY_SCOPE_AGENT);
}
__device__ __forceinline__ void astore_i(int* p, int v) {
    __hip_atomic_store(p, v, __ATOMIC_RELAXED, __HIP_MEMORY_SCOPE_AGENT);
}

// Coherent 16B load (async — must waitvm0() before using the result).
__device__ __forceinline__ float4 cload4(const float* p) {
    float4 v;
    asm volatile("global_load_dwordx4 %0, %1, off sc0 sc1" : "=v"(v) : "v"(p));
    return v;
}
__device__ __forceinline__ void waitvm0() {
    asm volatile("s_waitcnt vmcnt(0)" ::: "memory");
}

// ---------------------------------------------------------------------------
__global__ __launch_bounds__(256) void news_kernel(
    const float* __restrict__ in, const float* __restrict__ nW,
    const float* __restrict__ nb, float* __restrict__ x)
{
    int out_idx = blockIdx.x * 4 + (threadIdx.x >> 6);
    int lane = threadIdx.x & 63;
    const float4* src = (const float4*)(in + (size_t)out_idx * E);
    float4 a = src[lane];
    float4 wv = ((const float4*)nW)[lane];
    float s = a.x * wv.x + a.y * wv.y + a.z * wv.z + a.w * wv.w;
    s = waveReduceSum(s);
    if (lane == 0) x[out_idx] = s + nb[0];
}

// ---------------------------------------------------------------------------
__global__ __launch_bounds__(64) void z2_kernel(
    const float* __restrict__ x, const float* __restrict__ A2,
    const float* __restrict__ b2, float* __restrict__ z2)
{
    int b = blockIdx.x >> 7;
    int i = blockIdx.x & 127;
    int s = threadIdx.x;
    __shared__ float xs[T];
    xs[s] = x[((size_t)b * T + s) * IDIM + i];
    __syncthreads();
    float acc = b2[s];
    const float* arow = A2 + s * T;
#pragma unroll 8
    for (int tt = 0; tt < T; ++tt) acc += xs[tt] * arow[tt];
    z2[((size_t)b * IDIM + i) * T + s] = acc;
}

// ---------------------------------------------------------------------------
// Flag-array split barrier (per-quarter, 64 blocks). No atomics.
// Flags at 16 B stride: a quarter's 64 flags span 16 cache lines — the hot
// qwait vector-poll touches few IF$ sectors. Payload visibility: each wave
// drains vmcnt at the arrive's __syncthreads before the flag store issues.
#define FLG_STRIDE 4    // 16 B between flags.
__device__ __forceinline__ void qarrive(int* cnt, int q, int ns, int ph) {
    __syncthreads();                     // all waves drain vmem before arrive
    if (threadIdx.x == NT - 1) {
        asm volatile("s_waitcnt vmcnt(0) lgkmcnt(0)" ::: "memory");
        astore_i(cnt + (q * 64 + ns) * FLG_STRIDE, ph);
    }
}
__device__ __forceinline__ void qwait(int* cnt, int q, int ph) {
    if (threadIdx.x >= NT - 64) {
        int lane = threadIdx.x & 63;
        const int* fp = cnt + (q * 64 + lane) * FLG_STRIDE;
        int spins = 0;
        while (!__all(aload_i(fp) >= ph)) {
            if (++spins > (1 << 16)) break;  // fail visibly, never hang
        }
    }
    __syncthreads();
}

// ---------------------------------------------------------------------------
// Persistent scan — R18 chassis (512 thr, flag-array split barriers, de-dup
// attn, XCD-pair quarters, z1 2-row ILP) with two critical-path cuts:
// (1) x_t prefetched at step start (was a cold coherent load at the END of
//     the serial attn chain, right before the wbuf store barrier #1 gates);
// (2) b1 staged in LDS one-time (was per-step L2 scalar reads on the z1
//     lane-0 path).
// VGPR-cliff rule (R9/R10/R11): no live ranges extended across phases —
// the xt prefetch is 2 transient VGPRs in wave 0, consumed within phase A.
__global__ __launch_bounds__(NT, 1) void scan_kernel(
    const float* __restrict__ x, const float* __restrict__ z2,
    const float* __restrict__ A1, const float* __restrict__ b1,
    const float* __restrict__ a3w,
    const float* __restrict__ Wih, const float* __restrict__ Whh,
    const float* __restrict__ bih, const float* __restrict__ bhh,
    float* __restrict__ wbuf, float* __restrict__ hbuf, float* __restrict__ cbuf,
    int* __restrict__ cnt, float* __restrict__ out)
{
    __shared__ float pool[POOL_F];
    float* Wlds = pool + OFF_W;
    float* At4  = pool + OFF_A;
    float* hcs  = pool + OFF_HC;
    float* z1s  = pool + OFF_Z1;
    float* redl = pool + OFF_RED;
    float* blds = pool + OFF_BI;
    float* b1l  = pool + OFF_B1L;

    const int tid  = threadIdx.x;
    const int bid  = blockIdx.x;
    const int lane = tid & 63, wave = tid >> 6;
    const int q = bid & 3, ns = bid >> 2;      // XCD-pair-local quarters
    const int b0 = q * 32, n0 = ns * 8;
    const int ab = b0 + (ns >> 1);             // attn batch
    const bool is_attn = ((ns & 1) == 0);      // one attn block per batch
    const int jg = lane & 7, bg = lane >> 3;   // compute tile coords
    const int half = tid >> 8;                 // h-staging: 2 halves x 2 chunks
    const int sbh = (tid & 255) >> 3;          // batch row 0..31
    const int st8 = tid & 7;

    // one-time: weight slice (cols j = g*512 + n0 + nn; 4 gates x 8 n)
    for (int idx = tid; idx < 640 * 32; idx += NT) {
        int jj = idx / 640, k = idx - jj * 640;
        int j = (jj >> 3) * 512 + n0 + (jj & 7);
        Wlds[k * 32 + jj] = (k < 128) ? Wih[(size_t)j * 128 + k]
                                      : Whh[(size_t)j * 512 + (k - 128)];
    }
    if (tid < 32) {
        int j = (tid >> 3) * 512 + n0 + (tid & 7);
        blds[tid] = bih[j] + bhh[j];
    }
    if (tid < 64) b1l[tid] = b1[tid];          // t-invariant bias staged once

    // block-local cell state: thread tid<256 owns c[b0 + (tid>>3)][n0 + (tid&7)]
    float cown = 0.f;

    int ph = 0;
    for (int t = 0; t < T; ++t) {
        // -------- issue coherent prefetches: h-tile + x_t (hide under attn)
        float4 hv[8];
        {
            const float* hrow = hbuf + (size_t)(b0 + sbh) * H + half * 256;
#pragma unroll
            for (int cc = 0; cc < 2; ++cc)
#pragma unroll
                for (int qq = 0; qq < 4; ++qq)
                    hv[cc * 4 + qq] = cload4(hrow + cc * 128 + (st8 + 8 * qq) * 4);
        }
        float xs0 = 0.f, xs1 = 0.f;
        if (is_attn && wave == 0) {
            const float* xt = x + ((size_t)ab * T + t) * IDIM;
            xs0 = aload(xt + lane);
            xs1 = aload(xt + lane + 64);
        }

        // -------- phase A: attention (EVEN-ns blocks only; full batch) ------
        if (is_attn) {
            hcs[tid]     = aload(hbuf + (size_t)ab * H + tid);
            hcs[H + tid] = aload(cbuf + (size_t)ab * H + tid);
            __syncthreads();
            // z1: 2-row ILP — paired rows share the LDS operand read and
            // stream two independent A1 rows from L2 concurrently.
            for (int r = 0; r < 4; ++r) {
                int t0 = r * 16 + wave;
                int t1 = t0 + 8;
                const float* r0 = A1 + (size_t)t0 * (2 * H);
                const float* r1 = A1 + (size_t)t1 * (2 * H);
                float p0 = 0.f, p1 = 0.f;
#pragma unroll
                for (int qq = 0; qq < 16; ++qq) {
                    float hcv = hcs[lane + qq * 64];
                    p0 += r0[lane + qq * 64] * hcv;
                    p1 += r1[lane + qq * 64] * hcv;
                }
                p0 = waveReduceSum(p0);
                p1 = waveReduceSum(p1);
                if (lane == 0) {
                    z1s[t0] = p0 + b1l[t0];
                    z1s[t1] = p1 + b1l[t1];
                }
            }
            __syncthreads();
            // z3: 4 threads per driver row, 16 t each (R4-verified indexing)
            int i = tid >> 2, qt = tid & 3;
            const float* z2r = z2 + ((size_t)ab * IDIM + i) * T + qt * 16;
            const float* z1p = z1s + qt * 16;
            const float* a3p = a3w + qt * 16;
            float accz = 0.f;
#pragma unroll
            for (int qq = 0; qq < 4; ++qq) {
                float4 zv  = *(const float4*)(z2r + qq * 4);
                float4 z1v = *(const float4*)(z1p + qq * 4);
                float4 a3v = *(const float4*)(a3p + qq * 4);
                accz += fast_tanh(z1v.x + zv.x) * a3v.x
                      + fast_tanh(z1v.y + zv.y) * a3v.y
                      + fast_tanh(z1v.z + zv.z) * a3v.z
                      + fast_tanh(z1v.w + zv.w) * a3v.w;
            }
            accz += __shfl_xor(accz, 1, 64);
            accz += __shfl_xor(accz, 2, 64);
            if (qt == 0) redl[i] = accz;
            __syncthreads();
            if (wave == 0) {
                float v0 = redl[lane], v1 = redl[lane + 64];
                float m = fmaxf(v0, v1);
                for (int off = 32; off > 0; off >>= 1)
                    m = fmaxf(m, __shfl_xor(m, off, 64));
                float e0 = __expf(v0 - m), e1 = __expf(v1 - m);
                float inv = 1.0f / waveReduceSum(e0 + e1);
                astore(wbuf + ab * IDIM + lane,      e0 * inv * xs0);
                astore(wbuf + ab * IDIM + lane + 64, e1 * inv * xs1);
            }
        }

        // -------- ARRIVE #1 (wbuf published); flags settle under B1 ---------
        ++ph;
        qarrive(cnt, q, ns, ph);

        // -------- stage h-tile into LDS (transposed, stride-34) -------------
        waitvm0();
        {
#pragma unroll
            for (int cc = 0; cc < 2; ++cc)
#pragma unroll
                for (int qq = 0; qq < 4; ++qq) {
                    float4 v = hv[cc * 4 + qq];
                    float* d = At4 + (half * 2 + cc) * AT_CH
                             + ((st8 + 8 * qq) * 4) * AT_STRIDE + sbh;
                    d[0] = v.x; d[AT_STRIDE] = v.y;
                    d[2 * AT_STRIDE] = v.z; d[3 * AT_STRIDE] = v.w;
                }
        }
        __syncthreads();

        // -------- B1: h-part GEMM, wave k-split (64 kk each of 512) ---------
        float acc[4][4];   // [ji (j within group)][eb (b within group)]
#pragma unroll
        for (int a_ = 0; a_ < 4; ++a_)
#pragma unroll
            for (int b_ = 0; b_ < 4; ++b_) acc[a_][b_] = 0.f;
        {
            const float* Ab = At4 + (wave >> 1) * AT_CH
                            + ((wave & 1) * 64) * AT_STRIDE + bg * 4;
            const float* Wb = Wlds + (size_t)(128 + wave * 64) * 32 + jg * 4;
#pragma unroll 8
            for (int i = 0; i < 64; ++i) {
                float4 wv = *(const float4*)(Wb + i * 32);
                float2 a01 = *(const float2*)(Ab + i * AT_STRIDE);
                float2 a23 = *(const float2*)(Ab + i * AT_STRIDE + 2);
                float av[4] = {a01.x, a01.y, a23.x, a23.y};
                const float wj[4] = {wv.x, wv.y, wv.z, wv.w};
#pragma unroll
                for (int a_ = 0; a_ < 4; ++a_)
#pragma unroll
                    for (int b_ = 0; b_ < 4; ++b_)
                        acc[a_][b_] += wj[a_] * av[b_];
            }
        }

        qwait(cnt, q, ph);                    // wbuf ready (quarter-local)

        // -------- stage w-tile, B2: w-part GEMM (16 kk each of 128) ---------
        {
            const float* wrow = wbuf + (size_t)(b0 + (tid >> 4)) * IDIM;
            float4 w0 = cload4(wrow + (tid & 15) * 4);
            float4 w1 = cload4(wrow + ((tid & 15) + 16) * 4);
            waitvm0();
            int sbw = tid >> 4, st16 = tid & 15;
            float* d0 = At4 + (st16 * 4) * AT_STRIDE + sbw;
            d0[0] = w0.x; d0[AT_STRIDE] = w0.y;
            d0[2 * AT_STRIDE] = w0.z; d0[3 * AT_STRIDE] = w0.w;
            float* d1 = At4 + ((st16 + 16) * 4) * AT_STRIDE + sbw;
            d1[0] = w1.x; d1[AT_STRIDE] = w1.y;
            d1[2 * AT_STRIDE] = w1.z; d1[3 * AT_STRIDE] = w1.w;
        }
        __syncthreads();
        {
            const float* Ab = At4 + (wave * 16) * AT_STRIDE + bg * 4;
            const float* Wb = Wlds + (size_t)(wave * 16) * 32 + jg * 4;
#pragma unroll
            for (int i = 0; i < 16; ++i) {
                float4 wv = *(const float4*)(Wb + i * 32);
                float2 a01 = *(const float2*)(Ab + i * AT_STRIDE);
                float2 a23 = *(const float2*)(Ab + i * AT_STRIDE + 2);
                float av[4] = {a01.x, a01.y, a23.x, a23.y};
                const float wj[4] = {wv.x, wv.y, wv.z, wv.w};
#pragma unroll
                for (int a_ = 0; a_ < 4; ++a_)
#pragma unroll
                    for (int b_ = 0; b_ < 4; ++b_)
                        acc[a_][b_] += wj[a_] * av[b_];
            }
        }

        // -------- 8-way cross-wave k-reduce (stride-33 + jg-rotation) -------
        float* red4 = At4 + AT_CH;            // 8448 floats, chunks 1-2 (dead)
#pragma unroll
        for (int ji = 0; ji < 4; ++ji) {
            int r = jg * 4 + ji;
#pragma unroll
            for (int eb = 0; eb < 4; ++eb)
                red4[wave * 1056 + r * 33 + bg * 4 + ((eb + jg) & 3)] = acc[ji][eb];
        }
        __syncthreads();

        float* glds = At4;                    // chunk 0 (dead after B2)
        if (tid < 256) {
            int jj = tid >> 3, b8 = tid & 7;
            int rot = jj >> 2;
            float bias = blds[jj];
            float s[4] = {bias, bias, bias, bias};
#pragma unroll
            for (int w = 0; w < 8; ++w) {
                const float* rp = red4 + w * 1056 + jj * 33 + b8 * 4;
#pragma unroll
                for (int eb = 0; eb < 4; ++eb)
                    s[eb] += rp[(eb + rot) & 3];
            }
#pragma unroll
            for (int eb = 0; eb < 4; ++eb)
                glds[jj * 33 + b8 * 4 + eb] = s[eb];
        }
        __syncthreads();
        float hnew = 0.f;
        if (tid < 256) {
            int ub = tid >> 3, un = tid & 7;
            float ig = glds[(0 * 8 + un) * 33 + ub];
            float fg = glds[(1 * 8 + un) * 33 + ub];
            float gg = glds[(2 * 8 + un) * 33 + ub];
            float og = glds[(3 * 8 + un) * 33 + ub];
            int gb = b0 + ub, gn = n0 + un;
            float cnew = sigmoidf_(fg) * cown + sigmoidf_(ig) * tanhf(gg);
            hnew = sigmoidf_(og) * tanhf(cnew);
            cown = cnew;
            astore(cbuf + (size_t)gb * H + gn, cnew);
            astore(hbuf + (size_t)gb * H + gn, hnew);
        }

        // -------- ARRIVE #2 (h,c published); out-store under settle ---------
        ++ph;
        qarrive(cnt, q, ns, ph);
        if (tid < 256) {
            int gb = b0 + (tid >> 3), gn = n0 + (tid & 7);
            out[((size_t)gb * T + t) * H + gn] = hnew;
        }
        qwait(cnt, q, ph);                    // h_{t+1}, c_{t+1} ready
    }
}

// ---------------------------------------------------------------------------
extern "C" void kernel_launch(void* const* d_in, const int* in_sizes, int n_in,
                              void* d_out, int out_size, void* d_ws, size_t ws_size,
                              hipStream_t stream)
{
    const float* input  = (const float*)d_in[0];
    const float* news_W = (const float*)d_in[1];
    const float* news_b = (const float*)d_in[2];
    const float* A1     = (const float*)d_in[3];
    const float* b1     = (const float*)d_in[4];
    const float* A2     = (const float*)d_in[5];
    const float* b2     = (const float*)d_in[6];
    const float* a3w    = (const float*)d_in[7];
    // d_in[8] = attn3_b: softmax-invariant, unused
    const float* Wih    = (const float*)d_in[9];
    const float* Whh    = (const float*)d_in[10];
    const float* bih    = (const float*)d_in[11];
    const float* bhh    = (const float*)d_in[12];
    float* out = (float*)d_out;

    char* ws = (char*)d_ws;
    size_t off = 0;
    auto alloc = [&](size_t nelem) {
        float* p = (float*)(ws + off);
        off += ((nelem * 4 + 255) / 256) * 256;
        return p;
    };
    float* x    = alloc((size_t)B * T * IDIM);   // 4 MB
    float* z2   = alloc((size_t)B * IDIM * T);   // 4 MB
    float* wbuf = alloc((size_t)B * IDIM);       // 64 KB
    float* hbuf = alloc((size_t)B * H);          // single h buffer
    float* cbuf = alloc((size_t)B * H);          // single c buffer
    int*   cnt  = (int*)alloc(2048);             // 256 flags x 4-int stride

    hipMemsetAsync(hbuf, 0, (size_t)B * H * 4, stream);
    hipMemsetAsync(cbuf, 0, (size_t)B * H * 4, stream);
    hipMemsetAsync(cnt, 0, 2048 * 4, stream);

    news_kernel<<<B * T * IDIM / 4, 256, 0, stream>>>(input, news_W, news_b, x);
    z2_kernel<<<B * IDIM, 64, 0, stream>>>(x, A2, b2, z2);
    scan_kernel<<<256, NT, 0, stream>>>(x, z2, A1, b1, a3w, Wih, Whh, bih, bhh,
                                        wbuf, hbuf, cbuf, cnt, out);
}